// Round 1
// baseline (826.627 us; speedup 1.0000x reference)
//
#include <hip/hip_runtime.h>

#define LQ   21760
#define NBATCH 2
#define MROWS (NBATCH * LQ)   // 43520 rows for all GEMMs

// ---------------------------------------------------------------------------
// Generic fp32 GEMM:  C[M x N] = A[M x 256] @ B[256 x N] + bias[N]
// BM=64, BN=64, BK=16, 256 threads, 4x4 per thread. M%64==0, N%64==0 assumed.
// ---------------------------------------------------------------------------
__global__ __launch_bounds__(256) void gemm_k256(
    const float* __restrict__ A, const float* __restrict__ B,
    const float* __restrict__ bias, float* __restrict__ C,
    int M, int N)
{
    __shared__ float As[16][68];   // [k][row], padded
    __shared__ float Bs[16][68];   // [k][col], padded (68*4=272 bytes, 16B-aligned rows)

    const int tid = threadIdx.x;
    const int tx = tid & 15, ty = tid >> 4;
    const int bx = blockIdx.x;         // over N/64
    const int by = blockIdx.y;         // over M/64

    const int arow = tid >> 2;         // 0..63
    const int ak   = (tid & 3) << 2;   // 0,4,8,12
    const int bk   = tid >> 4;         // 0..15
    const int bcol = (tid & 15) << 2;  // 0..60

    const float* Ag = A + (long)(by * 64 + arow) * 256 + ak;
    const float* Bg = B + (long)bk * N + bx * 64 + bcol;

    float acc[4][4] = {};

    for (int k0 = 0; k0 < 256; k0 += 16) {
        float4 av = *(const float4*)(Ag + k0);
        float4 bv = *(const float4*)(Bg + (long)k0 * N);
        As[ak + 0][arow] = av.x;
        As[ak + 1][arow] = av.y;
        As[ak + 2][arow] = av.z;
        As[ak + 3][arow] = av.w;
        *(float4*)&Bs[bk][bcol] = bv;
        __syncthreads();
#pragma unroll
        for (int k = 0; k < 16; ++k) {
            float4 a4 = *(const float4*)&As[k][ty * 4];
            float4 b4 = *(const float4*)&Bs[k][tx * 4];
            float a[4] = {a4.x, a4.y, a4.z, a4.w};
            float b[4] = {b4.x, b4.y, b4.z, b4.w};
#pragma unroll
            for (int i = 0; i < 4; ++i)
#pragma unroll
                for (int j = 0; j < 4; ++j)
                    acc[i][j] = fmaf(a[i], b[j], acc[i][j]);
        }
        __syncthreads();
    }

    float4 b4 = *(const float4*)&bias[bx * 64 + tx * 4];
#pragma unroll
    for (int i = 0; i < 4; ++i) {
        float4 o;
        o.x = acc[i][0] + b4.x;
        o.y = acc[i][1] + b4.y;
        o.z = acc[i][2] + b4.z;
        o.w = acc[i][3] + b4.w;
        *(float4*)&C[(long)(by * 64 + ty * 4 + i) * N + bx * 64 + tx * 4] = o;
    }
}

// ---------------------------------------------------------------------------
// Fused softmax + location + bilinear sampling core.
// One wave (64 lanes) per task t = ((n*Lq + q)*8 + m).
// lane = d + 32*half: d = channel 0..31, half picks x-corner (x0 / x0+1).
// Writes acc (N, Lq, 256) with channel layout c = m*32 + d.
// ---------------------------------------------------------------------------
__global__ __launch_bounds__(256) void ms_sample_kernel(
    const float* __restrict__ value,    // (N, 21760, 256)
    const float* __restrict__ offraw,   // (N, Lq, 256)  [m][l][p][xy]
    const float* __restrict__ attnraw,  // (N, Lq, 128)  [m][l*4+p] logits
    const float* __restrict__ refpts,   // (N, Lq, 4, 2)
    float* __restrict__ acc_out)        // (N, Lq, 256)
{
    const int lane = threadIdx.x & 63;
    const int wid  = threadIdx.x >> 6;
    const long t   = (long)blockIdx.x * 4 + wid;     // 0 .. 348159

    const int  m  = (int)(t & 7);
    const long qn = t >> 3;                          // n*Lq + q

    const int d    = lane & 31;
    const int half = lane >> 5;

    const float* att = attnraw + qn * 128 + m * 16;
    const float* off = offraw  + qn * 256 + m * 32;
    const float* ref = refpts  + qn * 8;

    // --- softmax over 16 logits (redundant per lane; uniform-address loads broadcast)
    float lg[16];
#pragma unroll
    for (int j = 0; j < 16; ++j) lg[j] = att[j];
    float mx = lg[0];
#pragma unroll
    for (int j = 1; j < 16; ++j) mx = fmaxf(mx, lg[j]);
    float s = 0.f;
#pragma unroll
    for (int j = 0; j < 16; ++j) { lg[j] = __expf(lg[j] - mx); s += lg[j]; }
    const float inv = 1.0f / s;

    const int Hs[4] = {128, 64, 32, 16};
    const int st[4] = {0, 16384, 20480, 21504};

    const long n = qn / LQ;
    const float* vbase = value + (n * LQ) * 256 + m * 32 + d;

    float acc = 0.f;

#pragma unroll
    for (int l = 0; l < 4; ++l) {
        const int Hh = Hs[l], Ww = Hs[l];      // square levels
        const float fW = (float)Ww, fH = (float)Hh;
        const float invW = 1.0f / fW, invH = 1.0f / fH;
        const float rx = ref[l * 2 + 0];
        const float ry = ref[l * 2 + 1];
#pragma unroll
        for (int p = 0; p < 4; ++p) {
            const float aw = lg[l * 4 + p] * inv;
            const float ox = off[l * 8 + p * 2 + 0];
            const float oy = off[l * 8 + p * 2 + 1];
            // loc in [0,1]; x = loc_x*W - 0.5 (align_corners=False)
            const float x = (rx + ox * invW) * fW - 0.5f;
            const float y = (ry + oy * invH) * fH - 0.5f;
            const float x0f = floorf(x), y0f = floorf(y);
            const float fx = x - x0f, fy = y - y0f;
            const int xi  = (int)x0f + half;
            const int yi0 = (int)y0f, yi1 = yi0 + 1;
            float wx = half ? fx : (1.0f - fx);
            if (xi < 0 || xi > Ww - 1) wx = 0.f;
            float wy0 = 1.0f - fy; if (yi0 < 0 || yi0 > Hh - 1) wy0 = 0.f;
            float wy1 = fy;        if (yi1 < 0 || yi1 > Hh - 1) wy1 = 0.f;
            const int xc  = min(max(xi, 0), Ww - 1);
            const int yc0 = min(max(yi0, 0), Hh - 1);
            const int yc1 = min(max(yi1, 0), Hh - 1);
            const float v0 = vbase[(long)(st[l] + yc0 * Ww + xc) * 256];
            const float v1 = vbase[(long)(st[l] + yc1 * Ww + xc) * 256];
            acc += aw * wx * (wy0 * v0 + wy1 * v1);
        }
    }

    // combine the two x-corner halves (lane d += lane d+32)
    acc += __shfl_xor(acc, 32);
    if (half == 0)
        acc_out[qn * 256 + m * 32 + d] = acc;
}

// ---------------------------------------------------------------------------
// In-place output projection (fallback when ws can't hold acc):
// io (43520 x 256) <- io @ W(256x256) + bias. One block owns 32 rows,
// stages them in LDS, computes all 256 output cols, writes back.
// ---------------------------------------------------------------------------
__global__ __launch_bounds__(256) void outproj_inplace(
    float* __restrict__ io, const float* __restrict__ W,
    const float* __restrict__ bias)
{
    __shared__ float As[32][260];  // rows staged, padded (260*4=1040B rows, 16B aligned)
    __shared__ float Bs[16][260];

    const int tid = threadIdx.x;
    const long rbase = (long)blockIdx.x * 32;

    // stage 32x256 rows: 2048 float4s, 8 per thread
#pragma unroll
    for (int i = 0; i < 8; ++i) {
        int f4 = i * 256 + tid;
        int r  = f4 >> 6;
        int c4 = (f4 & 63) << 2;
        float4 v = *(const float4*)&io[(rbase + r) * 256 + c4];
        *(float4*)&As[r][c4] = v;
    }
    __syncthreads();

    const int tx = tid & 15, ty = tid >> 4;  // rows ty*2+{0,1}; cols tx*4 + jj*64
    float acc[2][16] = {};

    for (int k0 = 0; k0 < 256; k0 += 16) {
#pragma unroll
        for (int i = 0; i < 4; ++i) {
            int f4 = i * 256 + tid;
            int kr = f4 >> 6;
            int c4 = (f4 & 63) << 2;
            float4 v = *(const float4*)&W[(long)(k0 + kr) * 256 + c4];
            *(float4*)&Bs[kr][c4] = v;
        }
        __syncthreads();
#pragma unroll
        for (int k = 0; k < 16; ++k) {
            float a0 = As[ty * 2 + 0][k0 + k];
            float a1 = As[ty * 2 + 1][k0 + k];
#pragma unroll
            for (int jj = 0; jj < 4; ++jj) {
                float4 b = *(const float4*)&Bs[k][tx * 4 + jj * 64];
                acc[0][jj * 4 + 0] = fmaf(a0, b.x, acc[0][jj * 4 + 0]);
                acc[0][jj * 4 + 1] = fmaf(a0, b.y, acc[0][jj * 4 + 1]);
                acc[0][jj * 4 + 2] = fmaf(a0, b.z, acc[0][jj * 4 + 2]);
                acc[0][jj * 4 + 3] = fmaf(a0, b.w, acc[0][jj * 4 + 3]);
                acc[1][jj * 4 + 0] = fmaf(a1, b.x, acc[1][jj * 4 + 0]);
                acc[1][jj * 4 + 1] = fmaf(a1, b.y, acc[1][jj * 4 + 1]);
                acc[1][jj * 4 + 2] = fmaf(a1, b.z, acc[1][jj * 4 + 2]);
                acc[1][jj * 4 + 3] = fmaf(a1, b.w, acc[1][jj * 4 + 3]);
            }
        }
        __syncthreads();
    }

#pragma unroll
    for (int i = 0; i < 2; ++i)
#pragma unroll
        for (int jj = 0; jj < 4; ++jj) {
            float4 b = *(const float4*)&bias[tx * 4 + jj * 64];
            float4 o;
            o.x = acc[i][jj * 4 + 0] + b.x;
            o.y = acc[i][jj * 4 + 1] + b.y;
            o.z = acc[i][jj * 4 + 2] + b.z;
            o.w = acc[i][jj * 4 + 3] + b.w;
            *(float4*)&io[(rbase + ty * 2 + i) * 256 + tx * 4 + jj * 64] = o;
        }
}

// ---------------------------------------------------------------------------
extern "C" void kernel_launch(void* const* d_in, const int* in_sizes, int n_in,
                              void* d_out, int out_size, void* d_ws, size_t ws_size,
                              hipStream_t stream)
{
    const float* query         = (const float*)d_in[0];
    const float* refpts        = (const float*)d_in[1];
    const float* input_flatten = (const float*)d_in[2];
    const float* W_off         = (const float*)d_in[3];
    const float* b_off         = (const float*)d_in[4];
    const float* W_attn        = (const float*)d_in[5];
    const float* b_attn        = (const float*)d_in[6];
    const float* W_val         = (const float*)d_in[7];
    const float* b_val         = (const float*)d_in[8];
    const float* W_out         = (const float*)d_in[9];
    const float* b_out         = (const float*)d_in[10];
    float* out = (float*)d_out;

    float* ws = (float*)d_ws;
    float* value   = ws;                           // 43520*256
    float* offraw  = value  + (long)MROWS * 256;   // 43520*256
    float* attnraw = offraw + (long)MROWS * 256;   // 43520*128
    float* accbuf  = attnraw + (long)MROWS * 128;  // 43520*256 (optional)

    const size_t need_with_acc =
        ((size_t)MROWS * 256 * 3 + (size_t)MROWS * 128) * sizeof(float);
    const bool has_acc = ws_size >= need_with_acc;

    dim3 blk(256);

    // 1) value = input_flatten @ W_val + b_val
    gemm_k256<<<dim3(4, MROWS / 64), blk, 0, stream>>>(input_flatten, W_val, b_val, value, MROWS, 256);
    // 2) offset logits = query @ W_off + b_off
    gemm_k256<<<dim3(4, MROWS / 64), blk, 0, stream>>>(query, W_off, b_off, offraw, MROWS, 256);
    // 3) attn logits = query @ W_attn + b_attn
    gemm_k256<<<dim3(2, MROWS / 64), blk, 0, stream>>>(query, W_attn, b_attn, attnraw, MROWS, 128);

    // 4) fused softmax + deformable sampling
    float* accp = has_acc ? accbuf : out;
    ms_sample_kernel<<<dim3((NBATCH * LQ * 8) / 4), blk, 0, stream>>>(
        value, offraw, attnraw, refpts, accp);

    // 5) out = acc @ W_out + b_out
    if (has_acc)
        gemm_k256<<<dim3(4, MROWS / 64), blk, 0, stream>>>(accbuf, W_out, b_out, out, MROWS, 256);
    else
        outproj_inplace<<<dim3(MROWS / 32), blk, 0, stream>>>(out, W_out, b_out);
}

// Round 2
// 441.293 us; speedup vs baseline: 1.8732x; 1.8732x over previous
//
#include <hip/hip_runtime.h>

#define LQ   21760
#define NBATCH 2
#define MROWS (NBATCH * LQ)   // 43520 rows for all GEMMs

// ---------------------------------------------------------------------------
// Generic fp32 GEMM:  C[M x N] = A[M x 256] @ B[256 x N] + bias[N]
// BM=64, BN=64, BK=16, 256 threads, 4x4 per thread. M%64==0, N%64==0 assumed.
// ---------------------------------------------------------------------------
__global__ __launch_bounds__(256) void gemm_k256(
    const float* __restrict__ A, const float* __restrict__ B,
    const float* __restrict__ bias, float* __restrict__ C,
    int M, int N)
{
    __shared__ float As[16][68];   // [k][row], padded
    __shared__ float Bs[16][68];   // [k][col], padded

    const int tid = threadIdx.x;
    const int tx = tid & 15, ty = tid >> 4;
    const int bx = blockIdx.x;         // over N/64
    const int by = blockIdx.y;         // over M/64

    const int arow = tid >> 2;         // 0..63
    const int ak   = (tid & 3) << 2;   // 0,4,8,12
    const int bk   = tid >> 4;         // 0..15
    const int bcol = (tid & 15) << 2;  // 0..60

    const float* Ag = A + (long)(by * 64 + arow) * 256 + ak;
    const float* Bg = B + (long)bk * N + bx * 64 + bcol;

    float acc[4][4] = {};

    for (int k0 = 0; k0 < 256; k0 += 16) {
        float4 av = *(const float4*)(Ag + k0);
        float4 bv = *(const float4*)(Bg + (long)k0 * N);
        As[ak + 0][arow] = av.x;
        As[ak + 1][arow] = av.y;
        As[ak + 2][arow] = av.z;
        As[ak + 3][arow] = av.w;
        *(float4*)&Bs[bk][bcol] = bv;
        __syncthreads();
#pragma unroll
        for (int k = 0; k < 16; ++k) {
            float4 a4 = *(const float4*)&As[k][ty * 4];
            float4 b4 = *(const float4*)&Bs[k][tx * 4];
            float a[4] = {a4.x, a4.y, a4.z, a4.w};
            float b[4] = {b4.x, b4.y, b4.z, b4.w};
#pragma unroll
            for (int i = 0; i < 4; ++i)
#pragma unroll
                for (int j = 0; j < 4; ++j)
                    acc[i][j] = fmaf(a[i], b[j], acc[i][j]);
        }
        __syncthreads();
    }

    float4 b4 = *(const float4*)&bias[bx * 64 + tx * 4];
#pragma unroll
    for (int i = 0; i < 4; ++i) {
        float4 o;
        o.x = acc[i][0] + b4.x;
        o.y = acc[i][1] + b4.y;
        o.z = acc[i][2] + b4.z;
        o.w = acc[i][3] + b4.w;
        *(float4*)&C[(long)(by * 64 + ty * 4 + i) * N + bx * 64 + tx * 4] = o;
    }
}

// ---------------------------------------------------------------------------
// Fused softmax + location + bilinear sampling core, producer/consumer wave.
// One wave per task t = ((n*Lq + q)*8 + m).
//
// Producer: lane l = 4*p + c computes metadata for point p (0..15), corner c:
//   addr = clamped pixel index within the flattened level stack,
//   wt   = softmax(p) * wx(c) * wy(c)   (0 if corner out of bounds).
// Consumer: lane = cg(0..7) + 8*slot(0..7), slot = 4*pp + c; 8 iterations
//   cover 16 points (2 per iter); each lane: 1 float4 value load + 4 FMA.
//   Metadata pulled from producer lane 8*it + slot via __shfl (ds_bpermute).
// Reduce float4 across slots (xor 8,16,32); lanes 0..7 write 32 channels.
// ---------------------------------------------------------------------------
__global__ __launch_bounds__(256) void ms_sample_kernel(
    const float* __restrict__ value,    // (N, 21760, 8, 32)
    const float* __restrict__ offraw,   // (N, Lq, 256)  [m][l][p][xy]
    const float* __restrict__ attnraw,  // (N, Lq, 128)  [m][l*4+p] logits
    const float* __restrict__ refpts,   // (N, Lq, 4, 2)
    float* __restrict__ acc_out)        // (N, Lq, 256)
{
    const int lane = threadIdx.x & 63;
    const int wid  = threadIdx.x >> 6;
    const long t   = (long)blockIdx.x * 4 + wid;     // 0 .. 348159

    const int  m  = (int)(t & 7);
    const long qn = t >> 3;                          // n*Lq + q

    // ---------------- producer: lane = 4*p + c ----------------
    const int p   = lane >> 2;        // point 0..15
    const int c   = lane & 3;         // corner
    const int cx  = c & 1, cy = c >> 1;
    const int lvl = p >> 2;           // level 0..3
    const int pt  = p & 3;            // point-in-level

    // softmax over the 16 logits: butterfly over the p-bits (2,3,4,5)
    float lg = attnraw[qn * 128 + m * 16 + p];
    float mx = lg;
    mx = fmaxf(mx, __shfl_xor(mx, 4));
    mx = fmaxf(mx, __shfl_xor(mx, 8));
    mx = fmaxf(mx, __shfl_xor(mx, 16));
    mx = fmaxf(mx, __shfl_xor(mx, 32));
    float e = __expf(lg - mx);
    float s = e;
    s += __shfl_xor(s, 4);
    s += __shfl_xor(s, 8);
    s += __shfl_xor(s, 16);
    s += __shfl_xor(s, 32);
    const float aw = e * (1.0f / s);

    const int W  = 128 >> lvl;                            // square levels
    const int st = (lvl == 0) ? 0 : (lvl == 1) ? 16384
                 : (lvl == 2) ? 20480 : 21504;
    const float fW = (float)W;

    const float2 rxy = *(const float2*)&refpts[qn * 8 + lvl * 2];
    const float2 oxy = *(const float2*)&offraw[qn * 256 + m * 32 + lvl * 8 + pt * 2];

    // x = (rx + ox/W)*W - 0.5  (align_corners=False), H == W
    const float x = fmaf(rxy.x, fW, oxy.x) - 0.5f;
    const float y = fmaf(rxy.y, fW, oxy.y) - 0.5f;
    const float x0f = floorf(x), y0f = floorf(y);
    const float fx = x - x0f, fy = y - y0f;
    const int xi = (int)x0f + cx;
    const int yi = (int)y0f + cy;
    const float wx = cx ? fx : (1.0f - fx);
    const float wy = cy ? fy : (1.0f - fy);
    const bool ok = (xi >= 0) & (xi <= W - 1) & (yi >= 0) & (yi <= W - 1);
    const float wt = ok ? aw * wx * wy : 0.0f;
    const int xc = min(max(xi, 0), W - 1);
    const int yc = min(max(yi, 0), W - 1);
    const int addr = st + yc * W + xc;                    // pixel index

    // ---------------- consumer: lane = cg + 8*slot ----------------
    const int cg   = lane & 7;        // float4 channel group
    const int slot = lane >> 3;       // 4*pp + c

    const long n = qn / LQ;
    const float4* v4 = (const float4*)(value + (n * (long)LQ) * 256 + m * 32);

    float4 acc = make_float4(0.f, 0.f, 0.f, 0.f);
#pragma unroll
    for (int it = 0; it < 8; ++it) {
        const int src = 8 * it + slot;
        const int   a = __shfl(addr, src);
        const float w = __shfl(wt, src);
        const float4 v = v4[(long)a * 64 + cg];
        acc.x = fmaf(w, v.x, acc.x);
        acc.y = fmaf(w, v.y, acc.y);
        acc.z = fmaf(w, v.z, acc.z);
        acc.w = fmaf(w, v.w, acc.w);
    }

    // reduce across slots (lanes with equal cg)
#pragma unroll
    for (int mask = 8; mask <= 32; mask <<= 1) {
        acc.x += __shfl_xor(acc.x, mask);
        acc.y += __shfl_xor(acc.y, mask);
        acc.z += __shfl_xor(acc.z, mask);
        acc.w += __shfl_xor(acc.w, mask);
    }

    if (lane < 8)
        *(float4*)&acc_out[qn * 256 + m * 32 + cg * 4] = acc;
}

// ---------------------------------------------------------------------------
// In-place output projection (fallback when ws can't hold acc).
// ---------------------------------------------------------------------------
__global__ __launch_bounds__(256) void outproj_inplace(
    float* __restrict__ io, const float* __restrict__ W,
    const float* __restrict__ bias)
{
    __shared__ float As[32][260];
    __shared__ float Bs[16][260];

    const int tid = threadIdx.x;
    const long rbase = (long)blockIdx.x * 32;

#pragma unroll
    for (int i = 0; i < 8; ++i) {
        int f4 = i * 256 + tid;
        int r  = f4 >> 6;
        int c4 = (f4 & 63) << 2;
        float4 v = *(const float4*)&io[(rbase + r) * 256 + c4];
        *(float4*)&As[r][c4] = v;
    }
    __syncthreads();

    const int tx = tid & 15, ty = tid >> 4;
    float acc[2][16] = {};

    for (int k0 = 0; k0 < 256; k0 += 16) {
#pragma unroll
        for (int i = 0; i < 4; ++i) {
            int f4 = i * 256 + tid;
            int kr = f4 >> 6;
            int c4 = (f4 & 63) << 2;
            float4 v = *(const float4*)&W[(long)(k0 + kr) * 256 + c4];
            *(float4*)&Bs[kr][c4] = v;
        }
        __syncthreads();
#pragma unroll
        for (int k = 0; k < 16; ++k) {
            float a0 = As[ty * 2 + 0][k0 + k];
            float a1 = As[ty * 2 + 1][k0 + k];
#pragma unroll
            for (int jj = 0; jj < 4; ++jj) {
                float4 b = *(const float4*)&Bs[k][tx * 4 + jj * 64];
                acc[0][jj * 4 + 0] = fmaf(a0, b.x, acc[0][jj * 4 + 0]);
                acc[0][jj * 4 + 1] = fmaf(a0, b.y, acc[0][jj * 4 + 1]);
                acc[0][jj * 4 + 2] = fmaf(a0, b.z, acc[0][jj * 4 + 2]);
                acc[0][jj * 4 + 3] = fmaf(a0, b.w, acc[0][jj * 4 + 3]);
                acc[1][jj * 4 + 0] = fmaf(a1, b.x, acc[1][jj * 4 + 0]);
                acc[1][jj * 4 + 1] = fmaf(a1, b.y, acc[1][jj * 4 + 1]);
                acc[1][jj * 4 + 2] = fmaf(a1, b.z, acc[1][jj * 4 + 2]);
                acc[1][jj * 4 + 3] = fmaf(a1, b.w, acc[1][jj * 4 + 3]);
            }
        }
        __syncthreads();
    }

#pragma unroll
    for (int i = 0; i < 2; ++i)
#pragma unroll
        for (int jj = 0; jj < 4; ++jj) {
            float4 b = *(const float4*)&bias[tx * 4 + jj * 64];
            float4 o;
            o.x = acc[i][jj * 4 + 0] + b.x;
            o.y = acc[i][jj * 4 + 1] + b.y;
            o.z = acc[i][jj * 4 + 2] + b.z;
            o.w = acc[i][jj * 4 + 3] + b.w;
            *(float4*)&io[(rbase + ty * 2 + i) * 256 + tx * 4 + jj * 64] = o;
        }
}

// ---------------------------------------------------------------------------
extern "C" void kernel_launch(void* const* d_in, const int* in_sizes, int n_in,
                              void* d_out, int out_size, void* d_ws, size_t ws_size,
                              hipStream_t stream)
{
    const float* query         = (const float*)d_in[0];
    const float* refpts        = (const float*)d_in[1];
    const float* input_flatten = (const float*)d_in[2];
    const float* W_off         = (const float*)d_in[3];
    const float* b_off         = (const float*)d_in[4];
    const float* W_attn        = (const float*)d_in[5];
    const float* b_attn        = (const float*)d_in[6];
    const float* W_val         = (const float*)d_in[7];
    const float* b_val         = (const float*)d_in[8];
    const float* W_out         = (const float*)d_in[9];
    const float* b_out         = (const float*)d_in[10];
    float* out = (float*)d_out;

    float* ws = (float*)d_ws;
    float* value   = ws;                           // 43520*256
    float* offraw  = value  + (long)MROWS * 256;   // 43520*256
    float* attnraw = offraw + (long)MROWS * 256;   // 43520*128
    float* accbuf  = attnraw + (long)MROWS * 128;  // 43520*256 (optional)

    const size_t need_with_acc =
        ((size_t)MROWS * 256 * 3 + (size_t)MROWS * 128) * sizeof(float);
    const bool has_acc = ws_size >= need_with_acc;

    dim3 blk(256);

    // 1) value = input_flatten @ W_val + b_val
    gemm_k256<<<dim3(4, MROWS / 64), blk, 0, stream>>>(input_flatten, W_val, b_val, value, MROWS, 256);
    // 2) offset logits = query @ W_off + b_off
    gemm_k256<<<dim3(4, MROWS / 64), blk, 0, stream>>>(query, W_off, b_off, offraw, MROWS, 256);
    // 3) attn logits = query @ W_attn + b_attn
    gemm_k256<<<dim3(2, MROWS / 64), blk, 0, stream>>>(query, W_attn, b_attn, attnraw, MROWS, 128);

    // 4) fused softmax + deformable sampling
    float* accp = has_acc ? accbuf : out;
    ms_sample_kernel<<<dim3((NBATCH * LQ * 8) / 4), blk, 0, stream>>>(
        value, offraw, attnraw, refpts, accp);

    // 5) out = acc @ W_out + b_out
    if (has_acc)
        gemm_k256<<<dim3(4, MROWS / 64), blk, 0, stream>>>(accbuf, W_out, b_out, out, MROWS, 256);
    else
        outproj_inplace<<<dim3(MROWS / 32), blk, 0, stream>>>(out, W_out, b_out);
}

// Round 3
// 223.392 us; speedup vs baseline: 3.7003x; 1.9754x over previous
//
#include <hip/hip_runtime.h>

#define LQ     21760
#define NBATCH 2
#define MROWS  (NBATCH * LQ)   // 43520 rows for all GEMMs

typedef __attribute__((ext_vector_type(8))) short bf16x8;
typedef __attribute__((ext_vector_type(4))) float f32x4;

__device__ __forceinline__ unsigned short f2bf(float f) {
    unsigned u = __builtin_bit_cast(unsigned, f);
    return (unsigned short)((u + 0x7fffu + ((u >> 16) & 1u)) >> 16);  // RNE
}
__device__ __forceinline__ float bf2f(unsigned short h) {
    return __builtin_bit_cast(float, (unsigned)h << 16);
}

// ---------------------------------------------------------------------------
// fp32 -> bf16 bulk convert (vectorized: float4 in, ushort4 out)
// ---------------------------------------------------------------------------
__global__ __launch_bounds__(256) void cvt_f32_bf16(
    const float* __restrict__ in, unsigned short* __restrict__ out, int n4)
{
    int i = blockIdx.x * 256 + threadIdx.x;
    if (i < n4) {
        float4 v = ((const float4*)in)[i];
        ushort4 o;
        o.x = f2bf(v.x); o.y = f2bf(v.y); o.z = f2bf(v.z); o.w = f2bf(v.w);
        ((ushort4*)out)[i] = o;
    }
}

// W[256][N] fp32 -> Wt[N][256] bf16 (transpose + convert; small)
__global__ __launch_bounds__(256) void cvt_w_t(
    const float* __restrict__ W, short* __restrict__ Wt, int N)
{
    int idx = blockIdx.x * 256 + threadIdx.x;   // over N*256
    if (idx < N * 256) {
        int nn = idx >> 8, k = idx & 255;
        Wt[idx] = (short)f2bf(W[(long)k * N + nn]);
    }
}

// ---------------------------------------------------------------------------
// bf16 MFMA GEMM: C[M x N] = Abf[M x 256] * Bt[N x 256]^T + bias
// Tile 128x128, 4 waves (2x2, 64x64/wave), BK=64, K=256 fixed, M=43520.
// LDS chunk-XOR swizzle (c ^ (r&7)) on both write and read (involution).
// OBF=1 -> write bf16 C, else fp32.
// ---------------------------------------------------------------------------
template <int OBF>
__global__ __launch_bounds__(256) void gemm_bf16_mfma(
    const short* __restrict__ Abf,   // [M][256] bf16
    const short* __restrict__ Bt,    // [N][256] bf16 (B transposed)
    const float* __restrict__ bias,  // [N]
    void* __restrict__ Cout, int N)
{
    __shared__ short Al[128 * 64];
    __shared__ short Bl[128 * 64];

    const int tid  = threadIdx.x;
    const int lane = tid & 63, wid = tid >> 6;
    const int wr = wid >> 1, wc = wid & 1;       // 2x2 wave grid
    const int bx = blockIdx.x, by = blockIdx.y;

    const long arow0 = (long)by * 128;
    const int  brow0 = bx * 128;

    f32x4 acc[4][4];
#pragma unroll
    for (int i = 0; i < 4; ++i)
#pragma unroll
        for (int j = 0; j < 4; ++j) acc[i][j] = (f32x4)0.f;

    bf16x8 ra[4], rb[4];
#pragma unroll
    for (int i = 0; i < 4; ++i) {               // prefetch K-tile 0
        int id = tid + i * 256, r = id >> 3, c = id & 7;
        ra[i] = *(const bf16x8*)(Abf + (arow0 + r) * 256 + c * 8);
        rb[i] = *(const bf16x8*)(Bt + (long)(brow0 + r) * 256 + c * 8);
    }

    for (int step = 0; step < 4; ++step) {
#pragma unroll
        for (int i = 0; i < 4; ++i) {
            int id = tid + i * 256, r = id >> 3, c = id & 7;
            *(bf16x8*)(Al + r * 64 + ((c ^ (r & 7)) * 8)) = ra[i];
            *(bf16x8*)(Bl + r * 64 + ((c ^ (r & 7)) * 8)) = rb[i];
        }
        __syncthreads();
        if (step < 3) {
            const int k0 = (step + 1) * 64;
#pragma unroll
            for (int i = 0; i < 4; ++i) {       // prefetch next K-tile
                int id = tid + i * 256, r = id >> 3, c = id & 7;
                ra[i] = *(const bf16x8*)(Abf + (arow0 + r) * 256 + k0 + c * 8);
                rb[i] = *(const bf16x8*)(Bt + (long)(brow0 + r) * 256 + k0 + c * 8);
            }
        }
#pragma unroll
        for (int kk = 0; kk < 2; ++kk) {
            const int g = lane >> 4;
            const int chunk = kk * 4 + g;       // 16B chunk along K
            bf16x8 af[4], bg[4];
#pragma unroll
            for (int mi = 0; mi < 4; ++mi) {
                int r = wr * 64 + mi * 16 + (lane & 15);
                af[mi] = *(const bf16x8*)(Al + r * 64 + ((chunk ^ (r & 7)) * 8));
            }
#pragma unroll
            for (int ni = 0; ni < 4; ++ni) {
                int r = wc * 64 + ni * 16 + (lane & 15);
                bg[ni] = *(const bf16x8*)(Bl + r * 64 + ((chunk ^ (r & 7)) * 8));
            }
#pragma unroll
            for (int mi = 0; mi < 4; ++mi)
#pragma unroll
                for (int ni = 0; ni < 4; ++ni)
                    acc[mi][ni] = __builtin_amdgcn_mfma_f32_16x16x32_bf16(
                        af[mi], bg[ni], acc[mi][ni], 0, 0, 0);
        }
        __syncthreads();
    }

    // epilogue: D col = lane&15 (+16*ni), row = (lane>>4)*4 + q (+16*mi)
#pragma unroll
    for (int mi = 0; mi < 4; ++mi) {
#pragma unroll
        for (int ni = 0; ni < 4; ++ni) {
            const int  col = bx * 128 + wc * 64 + ni * 16 + (lane & 15);
            const long row = (long)by * 128 + wr * 64 + mi * 16 + ((lane >> 4) * 4);
            const float b = bias[col];
#pragma unroll
            for (int q = 0; q < 4; ++q) {
                float v = acc[mi][ni][q] + b;
                if (OBF)
                    ((unsigned short*)Cout)[(row + q) * N + col] = f2bf(v);
                else
                    ((float*)Cout)[(row + q) * N + col] = v;
            }
        }
    }
}

// ---------------------------------------------------------------------------
// fp32 SIMT GEMM (fallback path only)
// ---------------------------------------------------------------------------
__global__ __launch_bounds__(256) void gemm_k256(
    const float* __restrict__ A, const float* __restrict__ B,
    const float* __restrict__ bias, float* __restrict__ C,
    int M, int N)
{
    __shared__ float As[16][68];
    __shared__ float Bs[16][68];

    const int tid = threadIdx.x;
    const int tx = tid & 15, ty = tid >> 4;
    const int bx = blockIdx.x, by = blockIdx.y;

    const int arow = tid >> 2;
    const int ak   = (tid & 3) << 2;
    const int bk   = tid >> 4;
    const int bcol = (tid & 15) << 2;

    const float* Ag = A + (long)(by * 64 + arow) * 256 + ak;
    const float* Bg = B + (long)bk * N + bx * 64 + bcol;

    float acc[4][4] = {};

    for (int k0 = 0; k0 < 256; k0 += 16) {
        float4 av = *(const float4*)(Ag + k0);
        float4 bv = *(const float4*)(Bg + (long)k0 * N);
        As[ak + 0][arow] = av.x;
        As[ak + 1][arow] = av.y;
        As[ak + 2][arow] = av.z;
        As[ak + 3][arow] = av.w;
        *(float4*)&Bs[bk][bcol] = bv;
        __syncthreads();
#pragma unroll
        for (int k = 0; k < 16; ++k) {
            float4 a4 = *(const float4*)&As[k][ty * 4];
            float4 b4 = *(const float4*)&Bs[k][tx * 4];
            float a[4] = {a4.x, a4.y, a4.z, a4.w};
            float b[4] = {b4.x, b4.y, b4.z, b4.w};
#pragma unroll
            for (int i = 0; i < 4; ++i)
#pragma unroll
                for (int j = 0; j < 4; ++j)
                    acc[i][j] = fmaf(a[i], b[j], acc[i][j]);
        }
        __syncthreads();
    }

    float4 b4 = *(const float4*)&bias[bx * 64 + tx * 4];
#pragma unroll
    for (int i = 0; i < 4; ++i) {
        float4 o;
        o.x = acc[i][0] + b4.x;
        o.y = acc[i][1] + b4.y;
        o.z = acc[i][2] + b4.z;
        o.w = acc[i][3] + b4.w;
        *(float4*)&C[(long)(by * 64 + ty * 4 + i) * N + bx * 64 + tx * 4] = o;
    }
}

// ---------------------------------------------------------------------------
// Fused softmax + sampling, producer/consumer wave. BF=1: bf16 off/attn/acc.
// ---------------------------------------------------------------------------
template <int BF>
__global__ __launch_bounds__(256) void ms_sample_kernel(
    const float* __restrict__ value,    // (N, 21760, 8, 32) fp32
    const void* __restrict__ offv,      // (N, Lq, 256)  [m][l][p][xy]
    const void* __restrict__ attnv,     // (N, Lq, 128)  [m][l*4+p] logits
    const float* __restrict__ refpts,   // (N, Lq, 4, 2)
    void* __restrict__ accv)            // (N, Lq, 256)
{
    const int lane = threadIdx.x & 63;
    const int wid  = threadIdx.x >> 6;
    const long t   = (long)blockIdx.x * 4 + wid;

    const int  m  = (int)(t & 7);
    const long qn = t >> 3;

    // ---------------- producer: lane = 4*p + c ----------------
    const int p   = lane >> 2;
    const int c   = lane & 3;
    const int cx  = c & 1, cy = c >> 1;
    const int lvl = p >> 2;
    const int pt  = p & 3;

    float lg;
    if (BF) lg = bf2f(((const unsigned short*)attnv)[qn * 128 + m * 16 + p]);
    else    lg = ((const float*)attnv)[qn * 128 + m * 16 + p];

    float mx = lg;
    mx = fmaxf(mx, __shfl_xor(mx, 4));
    mx = fmaxf(mx, __shfl_xor(mx, 8));
    mx = fmaxf(mx, __shfl_xor(mx, 16));
    mx = fmaxf(mx, __shfl_xor(mx, 32));
    float e = __expf(lg - mx);
    float s = e;
    s += __shfl_xor(s, 4);
    s += __shfl_xor(s, 8);
    s += __shfl_xor(s, 16);
    s += __shfl_xor(s, 32);
    const float aw = e * (1.0f / s);

    const int W  = 128 >> lvl;
    const int st = (lvl == 0) ? 0 : (lvl == 1) ? 16384
                 : (lvl == 2) ? 20480 : 21504;
    const float fW = (float)W;

    const float2 rxy = *(const float2*)&refpts[qn * 8 + lvl * 2];
    float ox, oy;
    if (BF) {
        unsigned oo = *(const unsigned*)((const unsigned short*)offv +
                                         qn * 256 + m * 32 + lvl * 8 + pt * 2);
        ox = bf2f((unsigned short)(oo & 0xffff));
        oy = bf2f((unsigned short)(oo >> 16));
    } else {
        float2 o2 = *(const float2*)((const float*)offv +
                                     qn * 256 + m * 32 + lvl * 8 + pt * 2);
        ox = o2.x; oy = o2.y;
    }

    const float x = fmaf(rxy.x, fW, ox) - 0.5f;
    const float y = fmaf(rxy.y, fW, oy) - 0.5f;
    const float x0f = floorf(x), y0f = floorf(y);
    const float fx = x - x0f, fy = y - y0f;
    const int xi = (int)x0f + cx;
    const int yi = (int)y0f + cy;
    const float wx = cx ? fx : (1.0f - fx);
    const float wy = cy ? fy : (1.0f - fy);
    const bool ok = (xi >= 0) & (xi <= W - 1) & (yi >= 0) & (yi <= W - 1);
    const float wt = ok ? aw * wx * wy : 0.0f;
    const int xc = min(max(xi, 0), W - 1);
    const int yc = min(max(yi, 0), W - 1);
    const int addr = st + yc * W + xc;

    // ---------------- consumer: lane = cg + 8*slot ----------------
    const int cg   = lane & 7;
    const int slot = lane >> 3;

    const long n = qn / LQ;
    const float4* v4 = (const float4*)(value + (n * (long)LQ) * 256 + m * 32);

    float4 acc = make_float4(0.f, 0.f, 0.f, 0.f);
#pragma unroll
    for (int it = 0; it < 8; ++it) {
        const int src = 8 * it + slot;
        const int   a = __shfl(addr, src);
        const float w = __shfl(wt, src);
        const float4 v = v4[(long)a * 64 + cg];
        acc.x = fmaf(w, v.x, acc.x);
        acc.y = fmaf(w, v.y, acc.y);
        acc.z = fmaf(w, v.z, acc.z);
        acc.w = fmaf(w, v.w, acc.w);
    }

#pragma unroll
    for (int mask = 8; mask <= 32; mask <<= 1) {
        acc.x += __shfl_xor(acc.x, mask);
        acc.y += __shfl_xor(acc.y, mask);
        acc.z += __shfl_xor(acc.z, mask);
        acc.w += __shfl_xor(acc.w, mask);
    }

    if (lane < 8) {
        if (BF) {
            ushort4 o;
            o.x = f2bf(acc.x); o.y = f2bf(acc.y);
            o.z = f2bf(acc.z); o.w = f2bf(acc.w);
            *(ushort4*)((unsigned short*)accv + qn * 256 + m * 32 + cg * 4) = o;
        } else {
            *(float4*)((float*)accv + qn * 256 + m * 32 + cg * 4) = acc;
        }
    }
}

// ---------------------------------------------------------------------------
// In-place output projection (fp32 fallback only)
// ---------------------------------------------------------------------------
__global__ __launch_bounds__(256) void outproj_inplace(
    float* __restrict__ io, const float* __restrict__ W,
    const float* __restrict__ bias)
{
    __shared__ float As[32][260];
    __shared__ float Bs[16][260];

    const int tid = threadIdx.x;
    const long rbase = (long)blockIdx.x * 32;

#pragma unroll
    for (int i = 0; i < 8; ++i) {
        int f4 = i * 256 + tid;
        int r  = f4 >> 6;
        int c4 = (f4 & 63) << 2;
        float4 v = *(const float4*)&io[(rbase + r) * 256 + c4];
        *(float4*)&As[r][c4] = v;
    }
    __syncthreads();

    const int tx = tid & 15, ty = tid >> 4;
    float acc[2][16] = {};

    for (int k0 = 0; k0 < 256; k0 += 16) {
#pragma unroll
        for (int i = 0; i < 4; ++i) {
            int f4 = i * 256 + tid;
            int kr = f4 >> 6;
            int c4 = (f4 & 63) << 2;
            float4 v = *(const float4*)&W[(long)(k0 + kr) * 256 + c4];
            *(float4*)&Bs[kr][c4] = v;
        }
        __syncthreads();
#pragma unroll
        for (int k = 0; k < 16; ++k) {
            float a0 = As[ty * 2 + 0][k0 + k];
            float a1 = As[ty * 2 + 1][k0 + k];
#pragma unroll
            for (int jj = 0; jj < 4; ++jj) {
                float4 b = *(const float4*)&Bs[k][tx * 4 + jj * 64];
                acc[0][jj * 4 + 0] = fmaf(a0, b.x, acc[0][jj * 4 + 0]);
                acc[0][jj * 4 + 1] = fmaf(a0, b.y, acc[0][jj * 4 + 1]);
                acc[0][jj * 4 + 2] = fmaf(a0, b.z, acc[0][jj * 4 + 2]);
                acc[0][jj * 4 + 3] = fmaf(a0, b.w, acc[0][jj * 4 + 3]);
                acc[1][jj * 4 + 0] = fmaf(a1, b.x, acc[1][jj * 4 + 0]);
                acc[1][jj * 4 + 1] = fmaf(a1, b.y, acc[1][jj * 4 + 1]);
                acc[1][jj * 4 + 2] = fmaf(a1, b.z, acc[1][jj * 4 + 2]);
                acc[1][jj * 4 + 3] = fmaf(a1, b.w, acc[1][jj * 4 + 3]);
            }
        }
        __syncthreads();
    }

#pragma unroll
    for (int i = 0; i < 2; ++i)
#pragma unroll
        for (int jj = 0; jj < 4; ++jj) {
            float4 b = *(const float4*)&bias[tx * 4 + jj * 64];
            float4 o;
            o.x = acc[i][jj * 4 + 0] + b.x;
            o.y = acc[i][jj * 4 + 1] + b.y;
            o.z = acc[i][jj * 4 + 2] + b.z;
            o.w = acc[i][jj * 4 + 3] + b.w;
            *(float4*)&io[(rbase + ty * 2 + i) * 256 + tx * 4 + jj * 64] = o;
        }
}

// ---------------------------------------------------------------------------
extern "C" void kernel_launch(void* const* d_in, const int* in_sizes, int n_in,
                              void* d_out, int out_size, void* d_ws, size_t ws_size,
                              hipStream_t stream)
{
    const float* query         = (const float*)d_in[0];
    const float* refpts        = (const float*)d_in[1];
    const float* input_flatten = (const float*)d_in[2];
    const float* W_off         = (const float*)d_in[3];
    const float* b_off         = (const float*)d_in[4];
    const float* W_attn        = (const float*)d_in[5];
    const float* b_attn        = (const float*)d_in[6];
    const float* W_val         = (const float*)d_in[7];
    const float* b_val         = (const float*)d_in[8];
    const float* W_out         = (const float*)d_in[9];
    const float* b_out         = (const float*)d_in[10];
    float* out = (float*)d_out;

    dim3 blk(256);
    const int n4 = (MROWS * 256) / 4;   // float4 count for 43520x256

    const size_t NEED_BF = 123011072ULL;
    if (ws_size >= NEED_BF) {
        // -------- bf16 MFMA path --------
        char* w = (char*)d_ws;
        float*          value  = (float*)w;                               // 44,564,480
        unsigned short* offbf  = (unsigned short*)(w + 44564480);         // 22,282,240
        unsigned short* attnbf = (unsigned short*)(w + 66846720);         // 11,141,120
        unsigned short* qbf    = (unsigned short*)(w + 77987840);         // 22,282,240
        unsigned short* inbf   = (unsigned short*)(w + 100270080);        // 22,282,240 (acc later)
        short*          Wtv    = (short*)(w + 122552320);
        short*          Wto    = (short*)(w + 122683392);
        short*          Wta    = (short*)(w + 122880000 - 65536);         // 122814464
        short*          Wtu    = (short*)(w + 122880000);

        cvt_f32_bf16<<<dim3((n4 + 255) / 256), blk, 0, stream>>>(input_flatten, inbf, n4);
        cvt_f32_bf16<<<dim3((n4 + 255) / 256), blk, 0, stream>>>(query, qbf, n4);
        cvt_w_t<<<dim3(256), blk, 0, stream>>>(W_val, Wtv, 256);
        cvt_w_t<<<dim3(256), blk, 0, stream>>>(W_off, Wto, 256);
        cvt_w_t<<<dim3(128), blk, 0, stream>>>(W_attn, Wta, 128);
        cvt_w_t<<<dim3(256), blk, 0, stream>>>(W_out, Wtu, 256);

        gemm_bf16_mfma<0><<<dim3(2, MROWS / 128), blk, 0, stream>>>(
            (const short*)inbf, Wtv, b_val, value, 256);
        gemm_bf16_mfma<1><<<dim3(2, MROWS / 128), blk, 0, stream>>>(
            (const short*)qbf, Wto, b_off, offbf, 256);
        gemm_bf16_mfma<1><<<dim3(1, MROWS / 128), blk, 0, stream>>>(
            (const short*)qbf, Wta, b_attn, attnbf, 128);

        // acc (bf16) reuses inbf (dead after value GEMM)
        ms_sample_kernel<1><<<dim3((NBATCH * LQ * 8) / 4), blk, 0, stream>>>(
            value, offbf, attnbf, refpts, inbf);

        gemm_bf16_mfma<0><<<dim3(2, MROWS / 128), blk, 0, stream>>>(
            (const short*)inbf, Wtu, b_out, out, 256);
    } else {
        // -------- fp32 fallback path --------
        float* ws = (float*)d_ws;
        float* value   = ws;
        float* offraw  = value  + (long)MROWS * 256;
        float* attnraw = offraw + (long)MROWS * 256;
        float* accbuf  = attnraw + (long)MROWS * 128;

        const size_t need_with_acc =
            ((size_t)MROWS * 256 * 3 + (size_t)MROWS * 128) * sizeof(float);
        const bool has_acc = ws_size >= need_with_acc;

        gemm_k256<<<dim3(4, MROWS / 64), blk, 0, stream>>>(input_flatten, W_val, b_val, value, MROWS, 256);
        gemm_k256<<<dim3(4, MROWS / 64), blk, 0, stream>>>(query, W_off, b_off, offraw, MROWS, 256);
        gemm_k256<<<dim3(2, MROWS / 64), blk, 0, stream>>>(query, W_attn, b_attn, attnraw, MROWS, 128);

        float* accp = has_acc ? accbuf : out;
        ms_sample_kernel<0><<<dim3((NBATCH * LQ * 8) / 4), blk, 0, stream>>>(
            value, offraw, attnraw, refpts, accp);

        if (has_acc)
            gemm_k256<<<dim3(4, MROWS / 64), blk, 0, stream>>>(accbuf, W_out, b_out, out, MROWS, 256);
        else
            outproj_inplace<<<dim3(MROWS / 32), blk, 0, stream>>>(out, W_out, b_out);
    }
}

// Round 4
// 206.261 us; speedup vs baseline: 4.0077x; 1.0831x over previous
//
#include <hip/hip_runtime.h>

#define LQ     21760
#define NBATCH 2
#define MROWS  (NBATCH * LQ)   // 43520 rows for all GEMMs

typedef __attribute__((ext_vector_type(8))) short bf16x8;
typedef __attribute__((ext_vector_type(4))) float f32x4;

__device__ __forceinline__ unsigned short f2bf(float f) {
    unsigned u = __builtin_bit_cast(unsigned, f);
    return (unsigned short)((u + 0x7fffu + ((u >> 16) & 1u)) >> 16);  // RNE
}
__device__ __forceinline__ float bf2f(unsigned short h) {
    return __builtin_bit_cast(float, (unsigned)h << 16);
}

// ---------------------------------------------------------------------------
// fp32 -> bf16 bulk convert (vectorized: float4 in, ushort4 out)
// ---------------------------------------------------------------------------
__global__ __launch_bounds__(256) void cvt_f32_bf16(
    const float* __restrict__ in, unsigned short* __restrict__ out, int n4)
{
    int i = blockIdx.x * 256 + threadIdx.x;
    if (i < n4) {
        float4 v = ((const float4*)in)[i];
        ushort4 o;
        o.x = f2bf(v.x); o.y = f2bf(v.y); o.z = f2bf(v.z); o.w = f2bf(v.w);
        ((ushort4*)out)[i] = o;
    }
}

// W[256][N] fp32 -> Wt[N][256] bf16 (transpose + convert; small)
__global__ __launch_bounds__(256) void cvt_w_t(
    const float* __restrict__ W, short* __restrict__ Wt, int N)
{
    int idx = blockIdx.x * 256 + threadIdx.x;   // over N*256
    if (idx < N * 256) {
        int nn = idx >> 8, k = idx & 255;
        Wt[idx] = (short)f2bf(W[(long)k * N + nn]);
    }
}

// ---------------------------------------------------------------------------
// bf16 MFMA GEMM: C[M x N] = Abf[M x 256] * Bt[N x 256]^T + bias
// Tile 128x128, 4 waves (2x2, 64x64/wave), BK=64, K=256 fixed.
// LDS chunk-XOR swizzle (c ^ (r&7)) on both write and read (involution).
// OBF=1 -> write bf16 C, else fp32.
// ---------------------------------------------------------------------------
template <int OBF>
__global__ __launch_bounds__(256) void gemm_bf16_mfma(
    const short* __restrict__ Abf,   // [M][256] bf16
    const short* __restrict__ Bt,    // [N][256] bf16 (B transposed)
    const float* __restrict__ bias,  // [N]
    void* __restrict__ Cout, int N)
{
    __shared__ short Al[128 * 64];
    __shared__ short Bl[128 * 64];

    const int tid  = threadIdx.x;
    const int lane = tid & 63, wid = tid >> 6;
    const int wr = wid >> 1, wc = wid & 1;       // 2x2 wave grid
    const int bx = blockIdx.x, by = blockIdx.y;

    const long arow0 = (long)by * 128;
    const int  brow0 = bx * 128;

    f32x4 acc[4][4];
#pragma unroll
    for (int i = 0; i < 4; ++i)
#pragma unroll
        for (int j = 0; j < 4; ++j) acc[i][j] = (f32x4)0.f;

    bf16x8 ra[4], rb[4];
#pragma unroll
    for (int i = 0; i < 4; ++i) {               // prefetch K-tile 0
        int id = tid + i * 256, r = id >> 3, c = id & 7;
        ra[i] = *(const bf16x8*)(Abf + (arow0 + r) * 256 + c * 8);
        rb[i] = *(const bf16x8*)(Bt + (long)(brow0 + r) * 256 + c * 8);
    }

    for (int step = 0; step < 4; ++step) {
#pragma unroll
        for (int i = 0; i < 4; ++i) {
            int id = tid + i * 256, r = id >> 3, c = id & 7;
            *(bf16x8*)(Al + r * 64 + ((c ^ (r & 7)) * 8)) = ra[i];
            *(bf16x8*)(Bl + r * 64 + ((c ^ (r & 7)) * 8)) = rb[i];
        }
        __syncthreads();
        if (step < 3) {
            const int k0 = (step + 1) * 64;
#pragma unroll
            for (int i = 0; i < 4; ++i) {       // prefetch next K-tile
                int id = tid + i * 256, r = id >> 3, c = id & 7;
                ra[i] = *(const bf16x8*)(Abf + (arow0 + r) * 256 + k0 + c * 8);
                rb[i] = *(const bf16x8*)(Bt + (long)(brow0 + r) * 256 + k0 + c * 8);
            }
        }
#pragma unroll
        for (int kk = 0; kk < 2; ++kk) {
            const int g = lane >> 4;
            const int chunk = kk * 4 + g;       // 16B chunk along K
            bf16x8 af[4], bg[4];
#pragma unroll
            for (int mi = 0; mi < 4; ++mi) {
                int r = wr * 64 + mi * 16 + (lane & 15);
                af[mi] = *(const bf16x8*)(Al + r * 64 + ((chunk ^ (r & 7)) * 8));
            }
#pragma unroll
            for (int ni = 0; ni < 4; ++ni) {
                int r = wc * 64 + ni * 16 + (lane & 15);
                bg[ni] = *(const bf16x8*)(Bl + r * 64 + ((chunk ^ (r & 7)) * 8));
            }
#pragma unroll
            for (int mi = 0; mi < 4; ++mi)
#pragma unroll
                for (int ni = 0; ni < 4; ++ni)
                    acc[mi][ni] = __builtin_amdgcn_mfma_f32_16x16x32_bf16(
                        af[mi], bg[ni], acc[mi][ni], 0, 0, 0);
        }
        __syncthreads();
    }

    // epilogue: D col = lane&15 (+16*ni), row = (lane>>4)*4 + q (+16*mi)
#pragma unroll
    for (int mi = 0; mi < 4; ++mi) {
#pragma unroll
        for (int ni = 0; ni < 4; ++ni) {
            const int  col = bx * 128 + wc * 64 + ni * 16 + (lane & 15);
            const long row = (long)by * 128 + wr * 64 + mi * 16 + ((lane >> 4) * 4);
            const float b = bias[col];
#pragma unroll
            for (int q = 0; q < 4; ++q) {
                float v = acc[mi][ni][q] + b;
                if (OBF)
                    ((unsigned short*)Cout)[(row + q) * N + col] = f2bf(v);
                else
                    ((float*)Cout)[(row + q) * N + col] = v;
            }
        }
    }
}

// ---------------------------------------------------------------------------
// Fused softmax + sampling, bf16 value path.
// Block b: m = b&7 (uniform), 4 waves handle qn = (b>>3)*4 + wid.
// Producer lane = 4*p + c -> meta = (addr16 << 16) | f16(weight).
//   addr = n*21760 + level_start + yc*W + xc  (< 43520, fits 16 bits)
// Consumer lane = cg(0..7) + 8*slot: 8 iters, 8B bf16x4 load per lane
//   (4 channels), fp32 FMA, butterfly-reduce over slots, lanes<8 write.
// Value base pointer is block-uniform (SGPR) -> 32-bit voffset addressing.
// ---------------------------------------------------------------------------
__global__ __launch_bounds__(256) void ms_sample_bf16(
    const unsigned short* __restrict__ valuebf, // (43520, 8, 32) bf16
    const unsigned short* __restrict__ offbf,   // (43520, 256) bf16
    const unsigned short* __restrict__ attnbf,  // (43520, 128) bf16
    const float* __restrict__ refpts,           // (43520, 4, 2)
    unsigned short* __restrict__ accbf)         // (43520, 256) bf16
{
    const int lane = threadIdx.x & 63;
    const int wid  = threadIdx.x >> 6;
    const int b    = blockIdx.x;
    const int m    = b & 7;                     // block-uniform head
    const int qn   = (b >> 3) * 4 + wid;        // 0..43519
    const int n    = (qn >= LQ) ? 1 : 0;

    // ---------------- producer: lane = 4*p + c ----------------
    const int p   = lane >> 2;
    const int c   = lane & 3;
    const int cx  = c & 1, cy = c >> 1;
    const int lvl = p >> 2;
    const int pt  = p & 3;

    float lg = bf2f(attnbf[qn * 128 + m * 16 + p]);
    float mx = lg;
    mx = fmaxf(mx, __shfl_xor(mx, 4));
    mx = fmaxf(mx, __shfl_xor(mx, 8));
    mx = fmaxf(mx, __shfl_xor(mx, 16));
    mx = fmaxf(mx, __shfl_xor(mx, 32));
    float e = __expf(lg - mx);
    float s = e;
    s += __shfl_xor(s, 4);
    s += __shfl_xor(s, 8);
    s += __shfl_xor(s, 16);
    s += __shfl_xor(s, 32);
    const float aw = e * (1.0f / s);

    const int W  = 128 >> lvl;
    const int st = (lvl == 0) ? 0 : (lvl == 1) ? 16384
                 : (lvl == 2) ? 20480 : 21504;
    const float fW = (float)W;

    const float2 rxy = *(const float2*)&refpts[qn * 8 + lvl * 2];
    unsigned oo = *(const unsigned*)(offbf + qn * 256 + m * 32 + lvl * 8 + pt * 2);
    const float ox = bf2f((unsigned short)(oo & 0xffff));
    const float oy = bf2f((unsigned short)(oo >> 16));

    const float x = fmaf(rxy.x, fW, ox) - 0.5f;
    const float y = fmaf(rxy.y, fW, oy) - 0.5f;
    const float x0f = floorf(x), y0f = floorf(y);
    const float fx = x - x0f, fy = y - y0f;
    const int xi = (int)x0f + cx;
    const int yi = (int)y0f + cy;
    const float wx = cx ? fx : (1.0f - fx);
    const float wy = cy ? fy : (1.0f - fy);
    const bool ok = (xi >= 0) & (xi <= W - 1) & (yi >= 0) & (yi <= W - 1);
    const float wt = ok ? aw * wx * wy : 0.0f;
    const int xc = min(max(xi, 0), W - 1);
    const int yc = min(max(yi, 0), W - 1);
    const int addr = n * 21760 + st + yc * W + xc;          // < 43520

    const unsigned short wh = __builtin_bit_cast(unsigned short, (_Float16)wt);
    const unsigned meta = ((unsigned)addr << 16) | (unsigned)wh;

    // ---------------- consumer: lane = cg + 8*slot ----------------
    const int cg   = lane & 7;
    const int slot = lane >> 3;

    const char* vb = (const char*)valuebf + m * 64;   // block-uniform (SGPR)
    const unsigned mc = (unsigned)(cg * 8);

    float a0 = 0.f, a1 = 0.f, a2 = 0.f, a3 = 0.f;
#pragma unroll
    for (int it = 0; it < 8; ++it) {
        const unsigned pm = (unsigned)__shfl((int)meta, 8 * it + slot);
        const float w = (float)__builtin_bit_cast(_Float16, (unsigned short)(pm & 0xffffu));
        const unsigned boff = ((pm >> 16) << 9) + mc;     // pixel*512 + cg*8
        const uint2 vv = *(const uint2*)(vb + boff);      // 4 bf16 channels
        a0 = fmaf(w, __builtin_bit_cast(float, vv.x << 16), a0);
        a1 = fmaf(w, __builtin_bit_cast(float, vv.x & 0xffff0000u), a1);
        a2 = fmaf(w, __builtin_bit_cast(float, vv.y << 16), a2);
        a3 = fmaf(w, __builtin_bit_cast(float, vv.y & 0xffff0000u), a3);
    }

#pragma unroll
    for (int mask = 8; mask <= 32; mask <<= 1) {
        a0 += __shfl_xor(a0, mask);
        a1 += __shfl_xor(a1, mask);
        a2 += __shfl_xor(a2, mask);
        a3 += __shfl_xor(a3, mask);
    }

    if (lane < 8) {
        ushort4 o;
        o.x = f2bf(a0); o.y = f2bf(a1); o.z = f2bf(a2); o.w = f2bf(a3);
        *(ushort4*)(accbf + (long)qn * 256 + m * 32 + cg * 4) = o;
    }
}

// ---------------------------------------------------------------------------
// fp32 SIMT GEMM (fallback path only)
// ---------------------------------------------------------------------------
__global__ __launch_bounds__(256) void gemm_k256(
    const float* __restrict__ A, const float* __restrict__ B,
    const float* __restrict__ bias, float* __restrict__ C,
    int M, int N)
{
    __shared__ float As[16][68];
    __shared__ float Bs[16][68];

    const int tid = threadIdx.x;
    const int tx = tid & 15, ty = tid >> 4;
    const int bx = blockIdx.x, by = blockIdx.y;

    const int arow = tid >> 2;
    const int ak   = (tid & 3) << 2;
    const int bk   = tid >> 4;
    const int bcol = (tid & 15) << 2;

    const float* Ag = A + (long)(by * 64 + arow) * 256 + ak;
    const float* Bg = B + (long)bk * N + bx * 64 + bcol;

    float acc[4][4] = {};

    for (int k0 = 0; k0 < 256; k0 += 16) {
        float4 av = *(const float4*)(Ag + k0);
        float4 bv = *(const float4*)(Bg + (long)k0 * N);
        As[ak + 0][arow] = av.x;
        As[ak + 1][arow] = av.y;
        As[ak + 2][arow] = av.z;
        As[ak + 3][arow] = av.w;
        *(float4*)&Bs[bk][bcol] = bv;
        __syncthreads();
#pragma unroll
        for (int k = 0; k < 16; ++k) {
            float4 a4 = *(const float4*)&As[k][ty * 4];
            float4 b4 = *(const float4*)&Bs[k][tx * 4];
            float a[4] = {a4.x, a4.y, a4.z, a4.w};
            float b[4] = {b4.x, b4.y, b4.z, b4.w};
#pragma unroll
            for (int i = 0; i < 4; ++i)
#pragma unroll
                for (int j = 0; j < 4; ++j)
                    acc[i][j] = fmaf(a[i], b[j], acc[i][j]);
        }
        __syncthreads();
    }

    float4 b4 = *(const float4*)&bias[bx * 64 + tx * 4];
#pragma unroll
    for (int i = 0; i < 4; ++i) {
        float4 o;
        o.x = acc[i][0] + b4.x;
        o.y = acc[i][1] + b4.y;
        o.z = acc[i][2] + b4.z;
        o.w = acc[i][3] + b4.w;
        *(float4*)&C[(long)(by * 64 + ty * 4 + i) * N + bx * 64 + tx * 4] = o;
    }
}

// ---------------------------------------------------------------------------
// fp32 sampling (fallback path only)
// ---------------------------------------------------------------------------
__global__ __launch_bounds__(256) void ms_sample_f32(
    const float* __restrict__ value,
    const float* __restrict__ offraw,
    const float* __restrict__ attnraw,
    const float* __restrict__ refpts,
    float* __restrict__ acc_out)
{
    const int lane = threadIdx.x & 63;
    const int wid  = threadIdx.x >> 6;
    const long t   = (long)blockIdx.x * 4 + wid;

    const int  m  = (int)(t & 7);
    const long qn = t >> 3;

    const int p   = lane >> 2;
    const int c   = lane & 3;
    const int cx  = c & 1, cy = c >> 1;
    const int lvl = p >> 2;
    const int pt  = p & 3;

    float lg = attnraw[qn * 128 + m * 16 + p];
    float mx = lg;
    mx = fmaxf(mx, __shfl_xor(mx, 4));
    mx = fmaxf(mx, __shfl_xor(mx, 8));
    mx = fmaxf(mx, __shfl_xor(mx, 16));
    mx = fmaxf(mx, __shfl_xor(mx, 32));
    float e = __expf(lg - mx);
    float s = e;
    s += __shfl_xor(s, 4);
    s += __shfl_xor(s, 8);
    s += __shfl_xor(s, 16);
    s += __shfl_xor(s, 32);
    const float aw = e * (1.0f / s);

    const int W  = 128 >> lvl;
    const int st = (lvl == 0) ? 0 : (lvl == 1) ? 16384
                 : (lvl == 2) ? 20480 : 21504;
    const float fW = (float)W;

    const float2 rxy = *(const float2*)&refpts[qn * 8 + lvl * 2];
    float2 o2 = *(const float2*)(offraw + qn * 256 + m * 32 + lvl * 8 + pt * 2);

    const float x = fmaf(rxy.x, fW, o2.x) - 0.5f;
    const float y = fmaf(rxy.y, fW, o2.y) - 0.5f;
    const float x0f = floorf(x), y0f = floorf(y);
    const float fx = x - x0f, fy = y - y0f;
    const int xi = (int)x0f + cx;
    const int yi = (int)y0f + cy;
    const float wx = cx ? fx : (1.0f - fx);
    const float wy = cy ? fy : (1.0f - fy);
    const bool ok = (xi >= 0) & (xi <= W - 1) & (yi >= 0) & (yi <= W - 1);
    const float wt = ok ? aw * wx * wy : 0.0f;
    const int xc = min(max(xi, 0), W - 1);
    const int yc = min(max(yi, 0), W - 1);
    const int addr = st + yc * W + xc;

    const int cg   = lane & 7;
    const int slot = lane >> 3;

    const long n = qn / LQ;
    const float4* v4 = (const float4*)(value + (n * (long)LQ) * 256 + m * 32);

    float4 acc = make_float4(0.f, 0.f, 0.f, 0.f);
#pragma unroll
    for (int it = 0; it < 8; ++it) {
        const int src = 8 * it + slot;
        const int   a = __shfl(addr, src);
        const float w = __shfl(wt, src);
        const float4 v = v4[(long)a * 64 + cg];
        acc.x = fmaf(w, v.x, acc.x);
        acc.y = fmaf(w, v.y, acc.y);
        acc.z = fmaf(w, v.z, acc.z);
        acc.w = fmaf(w, v.w, acc.w);
    }

#pragma unroll
    for (int mask = 8; mask <= 32; mask <<= 1) {
        acc.x += __shfl_xor(acc.x, mask);
        acc.y += __shfl_xor(acc.y, mask);
        acc.z += __shfl_xor(acc.z, mask);
        acc.w += __shfl_xor(acc.w, mask);
    }

    if (lane < 8)
        *(float4*)(acc_out + qn * 256 + m * 32 + cg * 4) = acc;
}

// ---------------------------------------------------------------------------
// In-place output projection (fp32 fallback only)
// ---------------------------------------------------------------------------
__global__ __launch_bounds__(256) void outproj_inplace(
    float* __restrict__ io, const float* __restrict__ W,
    const float* __restrict__ bias)
{
    __shared__ float As[32][260];
    __shared__ float Bs[16][260];

    const int tid = threadIdx.x;
    const long rbase = (long)blockIdx.x * 32;

#pragma unroll
    for (int i = 0; i < 8; ++i) {
        int f4 = i * 256 + tid;
        int r  = f4 >> 6;
        int c4 = (f4 & 63) << 2;
        float4 v = *(const float4*)&io[(rbase + r) * 256 + c4];
        *(float4*)&As[r][c4] = v;
    }
    __syncthreads();

    const int tx = tid & 15, ty = tid >> 4;
    float acc[2][16] = {};

    for (int k0 = 0; k0 < 256; k0 += 16) {
#pragma unroll
        for (int i = 0; i < 4; ++i) {
            int f4 = i * 256 + tid;
            int kr = f4 >> 6;
            int c4 = (f4 & 63) << 2;
            float4 v = *(const float4*)&W[(long)(k0 + kr) * 256 + c4];
            *(float4*)&Bs[kr][c4] = v;
        }
        __syncthreads();
#pragma unroll
        for (int k = 0; k < 16; ++k) {
            float a0 = As[ty * 2 + 0][k0 + k];
            float a1 = As[ty * 2 + 1][k0 + k];
#pragma unroll
            for (int jj = 0; jj < 4; ++jj) {
                float4 b = *(const float4*)&Bs[k][tx * 4 + jj * 64];
                acc[0][jj * 4 + 0] = fmaf(a0, b.x, acc[0][jj * 4 + 0]);
                acc[0][jj * 4 + 1] = fmaf(a0, b.y, acc[0][jj * 4 + 1]);
                acc[0][jj * 4 + 2] = fmaf(a0, b.z, acc[0][jj * 4 + 2]);
                acc[0][jj * 4 + 3] = fmaf(a0, b.w, acc[0][jj * 4 + 3]);
                acc[1][jj * 4 + 0] = fmaf(a1, b.x, acc[1][jj * 4 + 0]);
                acc[1][jj * 4 + 1] = fmaf(a1, b.y, acc[1][jj * 4 + 1]);
                acc[1][jj * 4 + 2] = fmaf(a1, b.z, acc[1][jj * 4 + 2]);
                acc[1][jj * 4 + 3] = fmaf(a1, b.w, acc[1][jj * 4 + 3]);
            }
        }
        __syncthreads();
    }

#pragma unroll
    for (int i = 0; i < 2; ++i)
#pragma unroll
        for (int jj = 0; jj < 4; ++jj) {
            float4 b = *(const float4*)&bias[tx * 4 + jj * 64];
            float4 o;
            o.x = acc[i][jj * 4 + 0] + b.x;
            o.y = acc[i][jj * 4 + 1] + b.y;
            o.z = acc[i][jj * 4 + 2] + b.z;
            o.w = acc[i][jj * 4 + 3] + b.w;
            *(float4*)&io[(rbase + ty * 2 + i) * 256 + tx * 4 + jj * 64] = o;
        }
}

// ---------------------------------------------------------------------------
extern "C" void kernel_launch(void* const* d_in, const int* in_sizes, int n_in,
                              void* d_out, int out_size, void* d_ws, size_t ws_size,
                              hipStream_t stream)
{
    const float* query         = (const float*)d_in[0];
    const float* refpts        = (const float*)d_in[1];
    const float* input_flatten = (const float*)d_in[2];
    const float* W_off         = (const float*)d_in[3];
    const float* b_off         = (const float*)d_in[4];
    const float* W_attn        = (const float*)d_in[5];
    const float* b_attn        = (const float*)d_in[6];
    const float* W_val         = (const float*)d_in[7];
    const float* b_val         = (const float*)d_in[8];
    const float* W_out         = (const float*)d_in[9];
    const float* b_out         = (const float*)d_in[10];
    float* out = (float*)d_out;

    dim3 blk(256);
    const int n4 = (MROWS * 256) / 4;   // float4 count for 43520x256

    const size_t NEED_BF = 100728832ULL;
    if (ws_size >= NEED_BF) {
        // -------- bf16 MFMA path --------
        char* w = (char*)d_ws;
        unsigned short* valuebf = (unsigned short*)w;                  // 22,282,240
        unsigned short* offbf   = (unsigned short*)(w + 22282240);     // 22,282,240
        unsigned short* attnbf  = (unsigned short*)(w + 44564480);     // 11,141,120
        unsigned short* qbf     = (unsigned short*)(w + 55705600);     // 22,282,240
        unsigned short* inbf    = (unsigned short*)(w + 77987840);     // 22,282,240 (acc later)
        short*          Wtv     = (short*)(w + 100270080);
        short*          Wto     = (short*)(w + 100401152);
        short*          Wta     = (short*)(w + 100532224);
        short*          Wtu     = (short*)(w + 100597760);

        cvt_f32_bf16<<<dim3((n4 + 255) / 256), blk, 0, stream>>>(input_flatten, inbf, n4);
        cvt_f32_bf16<<<dim3((n4 + 255) / 256), blk, 0, stream>>>(query, qbf, n4);
        cvt_w_t<<<dim3(256), blk, 0, stream>>>(W_val, Wtv, 256);
        cvt_w_t<<<dim3(256), blk, 0, stream>>>(W_off, Wto, 256);
        cvt_w_t<<<dim3(128), blk, 0, stream>>>(W_attn, Wta, 128);
        cvt_w_t<<<dim3(256), blk, 0, stream>>>(W_out, Wtu, 256);

        gemm_bf16_mfma<1><<<dim3(2, MROWS / 128), blk, 0, stream>>>(
            (const short*)inbf, Wtv, b_val, valuebf, 256);
        gemm_bf16_mfma<1><<<dim3(2, MROWS / 128), blk, 0, stream>>>(
            (const short*)qbf, Wto, b_off, offbf, 256);
        gemm_bf16_mfma<1><<<dim3(1, MROWS / 128), blk, 0, stream>>>(
            (const short*)qbf, Wta, b_attn, attnbf, 128);

        // acc (bf16) reuses inbf (dead after value GEMM)
        ms_sample_bf16<<<dim3(MROWS / 4 * 8), blk, 0, stream>>>(
            valuebf, offbf, attnbf, refpts, inbf);

        gemm_bf16_mfma<0><<<dim3(2, MROWS / 128), blk, 0, stream>>>(
            (const short*)inbf, Wtu, b_out, out, 256);
    } else {
        // -------- fp32 fallback path --------
        float* ws = (float*)d_ws;
        float* value   = ws;
        float* offraw  = value  + (long)MROWS * 256;
        float* attnraw = offraw + (long)MROWS * 256;
        float* accbuf  = attnraw + (long)MROWS * 128;

        const size_t need_with_acc =
            ((size_t)MROWS * 256 * 3 + (size_t)MROWS * 128) * sizeof(float);
        const bool has_acc = ws_size >= need_with_acc;

        gemm_k256<<<dim3(4, MROWS / 64), blk, 0, stream>>>(input_flatten, W_val, b_val, value, MROWS, 256);
        gemm_k256<<<dim3(4, MROWS / 64), blk, 0, stream>>>(query, W_off, b_off, offraw, MROWS, 256);
        gemm_k256<<<dim3(2, MROWS / 64), blk, 0, stream>>>(query, W_attn, b_attn, attnraw, MROWS, 128);

        float* accp = has_acc ? accbuf : out;
        ms_sample_f32<<<dim3((NBATCH * LQ * 8) / 4), blk, 0, stream>>>(
            value, offraw, attnraw, refpts, accp);

        if (has_acc)
            gemm_k256<<<dim3(4, MROWS / 64), blk, 0, stream>>>(accbuf, W_out, b_out, out, MROWS, 256);
        else
            outproj_inplace<<<dim3(MROWS / 32), blk, 0, stream>>>(out, W_out, b_out);
    }
}

// Round 5
// 192.703 us; speedup vs baseline: 4.2896x; 1.0704x over previous
//
#include <hip/hip_runtime.h>

#define LQ     21760
#define NBATCH 2
#define MROWS  (NBATCH * LQ)   // 43520 rows for all GEMMs

typedef __attribute__((ext_vector_type(8))) short bf16x8;
typedef __attribute__((ext_vector_type(4))) float f32x4;

__device__ __forceinline__ unsigned short f2bf(float f) {
    unsigned u = __builtin_bit_cast(unsigned, f);
    return (unsigned short)((u + 0x7fffu + ((u >> 16) & 1u)) >> 16);  // RNE
}
__device__ __forceinline__ float bf2f(unsigned short h) {
    return __builtin_bit_cast(float, (unsigned)h << 16);
}
__device__ __forceinline__ float f16lo(unsigned u) {
    return (float)__builtin_bit_cast(_Float16, (unsigned short)(u & 0xffffu));
}
__device__ __forceinline__ float f16hi(unsigned u) {
    return (float)__builtin_bit_cast(_Float16, (unsigned short)(u >> 16));
}

// ---------------------------------------------------------------------------
// All four weight matrices: W[256][N] fp32 -> Wt[N][256] bf16, one launch.
// Segments: Wtv (65536), Wcat rows 0-255 = W_off (65536),
//           Wcat rows 256-383 = W_attn (32768), Wtu (65536). Grid = 896.
// ---------------------------------------------------------------------------
__global__ __launch_bounds__(256) void cvt_wall(
    const float* __restrict__ Wv, const float* __restrict__ Wo,
    const float* __restrict__ Wa, const float* __restrict__ Wu,
    short* __restrict__ Wtv, short* __restrict__ Wcat, short* __restrict__ Wtu)
{
    int idx = blockIdx.x * 256 + threadIdx.x;
    if (idx < 65536) {
        int nn = idx >> 8, k = idx & 255;
        Wtv[idx] = (short)f2bf(Wv[k * 256 + nn]);
    } else if (idx < 131072) {
        int j = idx - 65536; int nn = j >> 8, k = j & 255;
        Wcat[j] = (short)f2bf(Wo[k * 256 + nn]);
    } else if (idx < 163840) {
        int j = idx - 131072; int nn = j >> 8, k = j & 255;
        Wcat[65536 + j] = (short)f2bf(Wa[k * 128 + nn]);
    } else if (idx < 229376) {
        int j = idx - 163840; int nn = j >> 8, k = j & 255;
        Wtu[j] = (short)f2bf(Wu[k * 256 + nn]);
    }
}

// ---------------------------------------------------------------------------
// MFMA GEMM: C[M x N] = A[M x 256] * Bt[N x 256]^T + bias
// Tile 128x128, 4 waves (2x2), BK=64, K=256 fixed.
// AF32=1: A is fp32, converted to bf16 during LDS staging (v_cvt_pk_bf16_f32).
// OMODE: 0 = f32 out, 1 = bf16 out, 2 = f16 out,
//        3 = split (cols<256 -> bf16 Cout stride 256; cols>=256 -> bf16 Cout2
//            stride 128, bias2) for the merged off+attn GEMM (N=384).
// LDS chunk-XOR swizzle (c ^ (r&7)) on both write and read (involution).
// ---------------------------------------------------------------------------
template <int AF32, int OMODE>
__global__ __launch_bounds__(256) void gemm_mfma(
    const void* __restrict__ Aptr,
    const short* __restrict__ Bt,
    const float* __restrict__ bias,
    const float* __restrict__ bias2,
    void* __restrict__ Cout,
    void* __restrict__ Cout2,
    int N)
{
    __shared__ short Al[128 * 64];
    __shared__ short Bl[128 * 64];

    const int tid  = threadIdx.x;
    const int lane = tid & 63, wid = tid >> 6;
    const int wr = wid >> 1, wc = wid & 1;
    const int bx = blockIdx.x, by = blockIdx.y;

    const long arow0 = (long)by * 128;
    const int  brow0 = bx * 128;

    const short* Abf = (const short*)Aptr;
    const float* Af  = (const float*)Aptr;

    f32x4 acc[4][4];
#pragma unroll
    for (int i = 0; i < 4; ++i)
#pragma unroll
        for (int j = 0; j < 4; ++j) acc[i][j] = (f32x4)0.f;

    bf16x8 ra[4], rb[4];
    float4 raf[4][2];

    // prefetch K-tile 0
#pragma unroll
    for (int i = 0; i < 4; ++i) {
        int id = tid + i * 256, r = id >> 3, c = id & 7;
        if (AF32) {
            raf[i][0] = *(const float4*)(Af + (arow0 + r) * 256 + c * 8);
            raf[i][1] = *(const float4*)(Af + (arow0 + r) * 256 + c * 8 + 4);
        } else {
            ra[i] = *(const bf16x8*)(Abf + (arow0 + r) * 256 + c * 8);
        }
        rb[i] = *(const bf16x8*)(Bt + (long)(brow0 + r) * 256 + c * 8);
    }

    for (int step = 0; step < 4; ++step) {
#pragma unroll
        for (int i = 0; i < 4; ++i) {
            int id = tid + i * 256, r = id >> 3, c = id & 7;
            bf16x8 av;
            if (AF32) {
                unsigned q0, q1, q2, q3;
                asm("v_cvt_pk_bf16_f32 %0, %1, %2" : "=v"(q0) : "v"(raf[i][0].x), "v"(raf[i][0].y));
                asm("v_cvt_pk_bf16_f32 %0, %1, %2" : "=v"(q1) : "v"(raf[i][0].z), "v"(raf[i][0].w));
                asm("v_cvt_pk_bf16_f32 %0, %1, %2" : "=v"(q2) : "v"(raf[i][1].x), "v"(raf[i][1].y));
                asm("v_cvt_pk_bf16_f32 %0, %1, %2" : "=v"(q3) : "v"(raf[i][1].z), "v"(raf[i][1].w));
                uint4 u = make_uint4(q0, q1, q2, q3);
                av = __builtin_bit_cast(bf16x8, u);
            } else {
                av = ra[i];
            }
            *(bf16x8*)(Al + r * 64 + ((c ^ (r & 7)) * 8)) = av;
            *(bf16x8*)(Bl + r * 64 + ((c ^ (r & 7)) * 8)) = rb[i];
        }
        __syncthreads();
        if (step < 3) {
            const int k0 = (step + 1) * 64;
#pragma unroll
            for (int i = 0; i < 4; ++i) {
                int id = tid + i * 256, r = id >> 3, c = id & 7;
                if (AF32) {
                    raf[i][0] = *(const float4*)(Af + (arow0 + r) * 256 + k0 + c * 8);
                    raf[i][1] = *(const float4*)(Af + (arow0 + r) * 256 + k0 + c * 8 + 4);
                } else {
                    ra[i] = *(const bf16x8*)(Abf + (arow0 + r) * 256 + k0 + c * 8);
                }
                rb[i] = *(const bf16x8*)(Bt + (long)(brow0 + r) * 256 + k0 + c * 8);
            }
        }
#pragma unroll
        for (int kk = 0; kk < 2; ++kk) {
            const int g = lane >> 4;
            const int chunk = kk * 4 + g;
            bf16x8 af[4], bg[4];
#pragma unroll
            for (int mi = 0; mi < 4; ++mi) {
                int r = wr * 64 + mi * 16 + (lane & 15);
                af[mi] = *(const bf16x8*)(Al + r * 64 + ((chunk ^ (r & 7)) * 8));
            }
#pragma unroll
            for (int ni = 0; ni < 4; ++ni) {
                int r = wc * 64 + ni * 16 + (lane & 15);
                bg[ni] = *(const bf16x8*)(Bl + r * 64 + ((chunk ^ (r & 7)) * 8));
            }
#pragma unroll
            for (int mi = 0; mi < 4; ++mi)
#pragma unroll
                for (int ni = 0; ni < 4; ++ni)
                    acc[mi][ni] = __builtin_amdgcn_mfma_f32_16x16x32_bf16(
                        af[mi], bg[ni], acc[mi][ni], 0, 0, 0);
        }
        __syncthreads();
    }

    // epilogue: D col = lane&15 (+16*ni), row = (lane>>4)*4 + q (+16*mi)
#pragma unroll
    for (int mi = 0; mi < 4; ++mi) {
#pragma unroll
        for (int ni = 0; ni < 4; ++ni) {
            const int  col = bx * 128 + wc * 64 + ni * 16 + (lane & 15);
            const long row = (long)by * 128 + wr * 64 + mi * 16 + ((lane >> 4) * 4);
            float b;
            if (OMODE == 3) b = (col < 256) ? bias[col] : bias2[col - 256];
            else            b = bias[col];
#pragma unroll
            for (int q = 0; q < 4; ++q) {
                float v = acc[mi][ni][q] + b;
                if (OMODE == 0) {
                    ((float*)Cout)[(row + q) * N + col] = v;
                } else if (OMODE == 1) {
                    ((unsigned short*)Cout)[(row + q) * N + col] = f2bf(v);
                } else if (OMODE == 2) {
                    ((unsigned short*)Cout)[(row + q) * N + col] =
                        __builtin_bit_cast(unsigned short, (_Float16)v);
                } else {
                    if (col < 256)
                        ((unsigned short*)Cout)[(row + q) * 256 + col] = f2bf(v);
                    else
                        ((unsigned short*)Cout2)[(row + q) * 128 + (col - 256)] = f2bf(v);
                }
            }
        }
    }
}

// ---------------------------------------------------------------------------
// Fused softmax + sampling; value in fp16.
// Block b: m = b&7 (uniform), 4 waves handle qn = (b>>3)*4 + wid.
// Producer lane = 4*p + c -> meta = (addr16 << 16) | f16(weight).
// Consumer: phase 1: 8 shuffles; phase 2: 8 independent 8B loads (in flight
// together); phase 3: fma_mix chain. Butterfly-reduce, lanes<8 write bf16.
// ---------------------------------------------------------------------------
__global__ __launch_bounds__(256) void ms_sample_f16v(
    const unsigned short* __restrict__ valuef16, // (43520, 8, 32) f16
    const unsigned short* __restrict__ offbf,    // (43520, 256) bf16
    const unsigned short* __restrict__ attnbf,   // (43520, 128) bf16
    const float* __restrict__ refpts,            // (43520, 4, 2)
    unsigned short* __restrict__ accbf)          // (43520, 256) bf16
{
    const int lane = threadIdx.x & 63;
    const int wid  = threadIdx.x >> 6;
    const int b    = blockIdx.x;
    const int m    = b & 7;                 // block-uniform head
    const int qn   = (b >> 3) * 4 + wid;    // 0..43519
    const int n    = (qn >= LQ) ? 1 : 0;

    // ---------------- producer: lane = 4*p + c ----------------
    const int p   = lane >> 2;
    const int c   = lane & 3;
    const int cx  = c & 1, cy = c >> 1;
    const int lvl = p >> 2;
    const int pt  = p & 3;

    float lg = bf2f(attnbf[qn * 128 + m * 16 + p]);
    float mx = lg;
    mx = fmaxf(mx, __shfl_xor(mx, 4));
    mx = fmaxf(mx, __shfl_xor(mx, 8));
    mx = fmaxf(mx, __shfl_xor(mx, 16));
    mx = fmaxf(mx, __shfl_xor(mx, 32));
    float e = __expf(lg - mx);
    float s = e;
    s += __shfl_xor(s, 4);
    s += __shfl_xor(s, 8);
    s += __shfl_xor(s, 16);
    s += __shfl_xor(s, 32);
    const float aw = e * (1.0f / s);

    const int W  = 128 >> lvl;
    const int st = (lvl == 0) ? 0 : (lvl == 1) ? 16384
                 : (lvl == 2) ? 20480 : 21504;
    const float fW = (float)W;

    const float2 rxy = *(const float2*)&refpts[qn * 8 + lvl * 2];
    unsigned oo = *(const unsigned*)(offbf + qn * 256 + m * 32 + lvl * 8 + pt * 2);
    const float ox = bf2f((unsigned short)(oo & 0xffff));
    const float oy = bf2f((unsigned short)(oo >> 16));

    const float x = fmaf(rxy.x, fW, ox) - 0.5f;
    const float y = fmaf(rxy.y, fW, oy) - 0.5f;
    const float x0f = floorf(x), y0f = floorf(y);
    const float fx = x - x0f, fy = y - y0f;
    const int xi = (int)x0f + cx;
    const int yi = (int)y0f + cy;
    const float wx = cx ? fx : (1.0f - fx);
    const float wy = cy ? fy : (1.0f - fy);
    const bool ok = (xi >= 0) & (xi <= W - 1) & (yi >= 0) & (yi <= W - 1);
    const float wt = ok ? aw * wx * wy : 0.0f;
    const int xc = min(max(xi, 0), W - 1);
    const int yc = min(max(yi, 0), W - 1);
    const int addr = n * 21760 + st + yc * W + xc;          // < 43520

    const unsigned short wh = __builtin_bit_cast(unsigned short, (_Float16)wt);
    const unsigned meta = ((unsigned)addr << 16) | (unsigned)wh;

    // ---------------- consumer: lane = cg + 8*slot ----------------
    const int cg   = lane & 7;
    const int slot = lane >> 3;
    const unsigned mc = (unsigned)(cg * 8);

    const char* vbu = (const char*)valuef16 + m * 64;   // block-uniform (SGPR)

    unsigned pm[8];
#pragma unroll
    for (int it = 0; it < 8; ++it)
        pm[it] = (unsigned)__shfl((int)meta, 8 * it + slot);

    uint2 vv[8];
#pragma unroll
    for (int it = 0; it < 8; ++it) {
        const unsigned voff = ((pm[it] >> 16) << 9) + mc;   // pixel*512 + cg*8
        vv[it] = *(const uint2*)(vbu + voff);
    }

    float a0 = 0.f, a1 = 0.f, a2 = 0.f, a3 = 0.f;
#pragma unroll
    for (int it = 0; it < 8; ++it) {
        const float w = f16lo(pm[it]);
        a0 = fmaf(f16lo(vv[it].x), w, a0);
        a1 = fmaf(f16hi(vv[it].x), w, a1);
        a2 = fmaf(f16lo(vv[it].y), w, a2);
        a3 = fmaf(f16hi(vv[it].y), w, a3);
    }

#pragma unroll
    for (int mask = 8; mask <= 32; mask <<= 1) {
        a0 += __shfl_xor(a0, mask);
        a1 += __shfl_xor(a1, mask);
        a2 += __shfl_xor(a2, mask);
        a3 += __shfl_xor(a3, mask);
    }

    if (lane < 8) {
        ushort4 o;
        o.x = f2bf(a0); o.y = f2bf(a1); o.z = f2bf(a2); o.w = f2bf(a3);
        *(ushort4*)(accbf + (long)qn * 256 + m * 32 + cg * 4) = o;
    }
}

// ---------------------------------------------------------------------------
// fp32 fallback kernels (used only if workspace is too small)
// ---------------------------------------------------------------------------
__global__ __launch_bounds__(256) void gemm_k256(
    const float* __restrict__ A, const float* __restrict__ B,
    const float* __restrict__ bias, float* __restrict__ C,
    int M, int N)
{
    __shared__ float As[16][68];
    __shared__ float Bs[16][68];

    const int tid = threadIdx.x;
    const int tx = tid & 15, ty = tid >> 4;
    const int bx = blockIdx.x, by = blockIdx.y;

    const int arow = tid >> 2;
    const int ak   = (tid & 3) << 2;
    const int bk   = tid >> 4;
    const int bcol = (tid & 15) << 2;

    const float* Ag = A + (long)(by * 64 + arow) * 256 + ak;
    const float* Bg = B + (long)bk * N + bx * 64 + bcol;

    float acc[4][4] = {};

    for (int k0 = 0; k0 < 256; k0 += 16) {
        float4 av = *(const float4*)(Ag + k0);
        float4 bv = *(const float4*)(Bg + (long)k0 * N);
        As[ak + 0][arow] = av.x;
        As[ak + 1][arow] = av.y;
        As[ak + 2][arow] = av.z;
        As[ak + 3][arow] = av.w;
        *(float4*)&Bs[bk][bcol] = bv;
        __syncthreads();
#pragma unroll
        for (int k = 0; k < 16; ++k) {
            float4 a4 = *(const float4*)&As[k][ty * 4];
            float4 b4 = *(const float4*)&Bs[k][tx * 4];
            float a[4] = {a4.x, a4.y, a4.z, a4.w};
            float bb[4] = {b4.x, b4.y, b4.z, b4.w};
#pragma unroll
            for (int i = 0; i < 4; ++i)
#pragma unroll
                for (int j = 0; j < 4; ++j)
                    acc[i][j] = fmaf(a[i], bb[j], acc[i][j]);
        }
        __syncthreads();
    }

    float4 b4 = *(const float4*)&bias[bx * 64 + tx * 4];
#pragma unroll
    for (int i = 0; i < 4; ++i) {
        float4 o;
        o.x = acc[i][0] + b4.x;
        o.y = acc[i][1] + b4.y;
        o.z = acc[i][2] + b4.z;
        o.w = acc[i][3] + b4.w;
        *(float4*)&C[(long)(by * 64 + ty * 4 + i) * N + bx * 64 + tx * 4] = o;
    }
}

__global__ __launch_bounds__(256) void ms_sample_f32(
    const float* __restrict__ value,
    const float* __restrict__ offraw,
    const float* __restrict__ attnraw,
    const float* __restrict__ refpts,
    float* __restrict__ acc_out)
{
    const int lane = threadIdx.x & 63;
    const int wid  = threadIdx.x >> 6;
    const long t   = (long)blockIdx.x * 4 + wid;

    const int  m  = (int)(t & 7);
    const long qn = t >> 3;

    const int p   = lane >> 2;
    const int c   = lane & 3;
    const int cx  = c & 1, cy = c >> 1;
    const int lvl = p >> 2;
    const int pt  = p & 3;

    float lg = attnraw[qn * 128 + m * 16 + p];
    float mx = lg;
    mx = fmaxf(mx, __shfl_xor(mx, 4));
    mx = fmaxf(mx, __shfl_xor(mx, 8));
    mx = fmaxf(mx, __shfl_xor(mx, 16));
    mx = fmaxf(mx, __shfl_xor(mx, 32));
    float e = __expf(lg - mx);
    float s = e;
    s += __shfl_xor(s, 4);
    s += __shfl_xor(s, 8);
    s += __shfl_xor(s, 16);
    s += __shfl_xor(s, 32);
    const float aw = e * (1.0f / s);

    const int W  = 128 >> lvl;
    const int st = (lvl == 0) ? 0 : (lvl == 1) ? 16384
                 : (lvl == 2) ? 20480 : 21504;
    const float fW = (float)W;

    const float2 rxy = *(const float2*)&refpts[qn * 8 + lvl * 2];
    float2 o2 = *(const float2*)(offraw + qn * 256 + m * 32 + lvl * 8 + pt * 2);

    const float x = fmaf(rxy.x, fW, o2.x) - 0.5f;
    const float y = fmaf(rxy.y, fW, o2.y) - 0.5f;
    const float x0f = floorf(x), y0f = floorf(y);
    const float fx = x - x0f, fy = y - y0f;
    const int xi = (int)x0f + cx;
    const int yi = (int)y0f + cy;
    const float wx = cx ? fx : (1.0f - fx);
    const float wy = cy ? fy : (1.0f - fy);
    const bool ok = (xi >= 0) & (xi <= W - 1) & (yi >= 0) & (yi <= W - 1);
    const float wt = ok ? aw * wx * wy : 0.0f;
    const int xc = min(max(xi, 0), W - 1);
    const int yc = min(max(yi, 0), W - 1);
    const int addr = st + yc * W + xc;

    const int cg   = lane & 7;
    const int slot = lane >> 3;

    const long nn = qn / LQ;
    const float4* v4 = (const float4*)(value + (nn * (long)LQ) * 256 + m * 32);

    float4 acc = make_float4(0.f, 0.f, 0.f, 0.f);
#pragma unroll
    for (int it = 0; it < 8; ++it) {
        const int src = 8 * it + slot;
        const int   a = __shfl(addr, src);
        const float w = __shfl(wt, src);
        const float4 v = v4[(long)a * 64 + cg];
        acc.x = fmaf(w, v.x, acc.x);
        acc.y = fmaf(w, v.y, acc.y);
        acc.z = fmaf(w, v.z, acc.z);
        acc.w = fmaf(w, v.w, acc.w);
    }

#pragma unroll
    for (int mask = 8; mask <= 32; mask <<= 1) {
        acc.x += __shfl_xor(acc.x, mask);
        acc.y += __shfl_xor(acc.y, mask);
        acc.z += __shfl_xor(acc.z, mask);
        acc.w += __shfl_xor(acc.w, mask);
    }

    if (lane < 8)
        *(float4*)(acc_out + qn * 256 + m * 32 + cg * 4) = acc;
}

__global__ __launch_bounds__(256) void outproj_inplace(
    float* __restrict__ io, const float* __restrict__ W,
    const float* __restrict__ bias)
{
    __shared__ float As[32][260];
    __shared__ float Bs[16][260];

    const int tid = threadIdx.x;
    const long rbase = (long)blockIdx.x * 32;

#pragma unroll
    for (int i = 0; i < 8; ++i) {
        int f4 = i * 256 + tid;
        int r  = f4 >> 6;
        int c4 = (f4 & 63) << 2;
        float4 v = *(const float4*)&io[(rbase + r) * 256 + c4];
        *(float4*)&As[r][c4] = v;
    }
    __syncthreads();

    const int tx = tid & 15, ty = tid >> 4;
    float acc[2][16] = {};

    for (int k0 = 0; k0 < 256; k0 += 16) {
#pragma unroll
        for (int i = 0; i < 4; ++i) {
            int f4 = i * 256 + tid;
            int kr = f4 >> 6;
            int c4 = (f4 & 63) << 2;
            float4 v = *(const float4*)&W[(long)(k0 + kr) * 256 + c4];
            *(float4*)&Bs[kr][c4] = v;
        }
        __syncthreads();
#pragma unroll
        for (int k = 0; k < 16; ++k) {
            float a0 = As[ty * 2 + 0][k0 + k];
            float a1 = As[ty * 2 + 1][k0 + k];
#pragma unroll
            for (int jj = 0; jj < 4; ++jj) {
                float4 b = *(const float4*)&Bs[k][tx * 4 + jj * 64];
                acc[0][jj * 4 + 0] = fmaf(a0, b.x, acc[0][jj * 4 + 0]);
                acc[0][jj * 4 + 1] = fmaf(a0, b.y, acc[0][jj * 4 + 1]);
                acc[0][jj * 4 + 2] = fmaf(a0, b.z, acc[0][jj * 4 + 2]);
                acc[0][jj * 4 + 3] = fmaf(a0, b.w, acc[0][jj * 4 + 3]);
                acc[1][jj * 4 + 0] = fmaf(a1, b.x, acc[1][jj * 4 + 0]);
                acc[1][jj * 4 + 1] = fmaf(a1, b.y, acc[1][jj * 4 + 1]);
                acc[1][jj * 4 + 2] = fmaf(a1, b.z, acc[1][jj * 4 + 2]);
                acc[1][jj * 4 + 3] = fmaf(a1, b.w, acc[1][jj * 4 + 3]);
            }
        }
        __syncthreads();
    }

#pragma unroll
    for (int i = 0; i < 2; ++i)
#pragma unroll
        for (int jj = 0; jj < 4; ++jj) {
            float4 b = *(const float4*)&bias[tx * 4 + jj * 64];
            float4 o;
            o.x = acc[i][jj * 4 + 0] + b.x;
            o.y = acc[i][jj * 4 + 1] + b.y;
            o.z = acc[i][jj * 4 + 2] + b.z;
            o.w = acc[i][jj * 4 + 3] + b.w;
            *(float4*)&io[(rbase + ty * 2 + i) * 256 + tx * 4 + jj * 64] = o;
        }
}

// ---------------------------------------------------------------------------
extern "C" void kernel_launch(void* const* d_in, const int* in_sizes, int n_in,
                              void* d_out, int out_size, void* d_ws, size_t ws_size,
                              hipStream_t stream)
{
    const float* query         = (const float*)d_in[0];
    const float* refpts        = (const float*)d_in[1];
    const float* input_flatten = (const float*)d_in[2];
    const float* W_off         = (const float*)d_in[3];
    const float* b_off         = (const float*)d_in[4];
    const float* W_attn        = (const float*)d_in[5];
    const float* b_attn        = (const float*)d_in[6];
    const float* W_val         = (const float*)d_in[7];
    const float* b_val         = (const float*)d_in[8];
    const float* W_out         = (const float*)d_in[9];
    const float* b_out         = (const float*)d_in[10];
    float* out = (float*)d_out;

    dim3 blk(256);

    const size_t NEED_BF = 78446592ULL;
    if (ws_size >= NEED_BF) {
        // -------- bf16/f16 MFMA path --------
        char* w = (char*)d_ws;
        unsigned short* valuef16 = (unsigned short*)w;               // 22,282,240
        unsigned short* offbf    = (unsigned short*)(w + 22282240);  // 22,282,240
        unsigned short* attnbf   = (unsigned short*)(w + 44564480);  // 11,141,120
        unsigned short* accbf    = (unsigned short*)(w + 55705600);  // 22,282,240
        short*          Wtv      = (short*)(w + 77987840);           // 131,072
        short*          Wcat     = (short*)(w + 78118912);           // 196,608
        short*          Wtu      = (short*)(w + 78315520);           // 131,072

        cvt_wall<<<dim3(896), blk, 0, stream>>>(
            W_val, W_off, W_attn, W_out, Wtv, Wcat, Wtu);

        // value = f16(input_flatten @ W_val + b_val)   (A fp32, fused cvt)
        gemm_mfma<1, 2><<<dim3(2, MROWS / 128), blk, 0, stream>>>(
            input_flatten, Wtv, b_val, nullptr, valuef16, nullptr, 256);
        // [off | attn] = bf16(query @ [W_off|W_attn] + bias), N=384 split
        gemm_mfma<1, 3><<<dim3(3, MROWS / 128), blk, 0, stream>>>(
            query, Wcat, b_off, b_attn, offbf, attnbf, 384);

        ms_sample_f16v<<<dim3(MROWS / 4 * 8), blk, 0, stream>>>(
            valuef16, offbf, attnbf, refpts, accbf);

        // out = f32(accbf @ W_out + b_out)
        gemm_mfma<0, 0><<<dim3(2, MROWS / 128), blk, 0, stream>>>(
            accbf, Wtu, b_out, nullptr, out, nullptr, 256);
    } else {
        // -------- fp32 fallback path --------
        float* ws = (float*)d_ws;
        float* value   = ws;
        float* offraw  = value  + (long)MROWS * 256;
        float* attnraw = offraw + (long)MROWS * 256;
        float* accbuf  = attnraw + (long)MROWS * 128;

        const size_t need_with_acc =
            ((size_t)MROWS * 256 * 3 + (size_t)MROWS * 128) * sizeof(float);
        const bool has_acc = ws_size >= need_with_acc;

        gemm_k256<<<dim3(4, MROWS / 64), blk, 0, stream>>>(input_flatten, W_val, b_val, value, MROWS, 256);
        gemm_k256<<<dim3(4, MROWS / 64), blk, 0, stream>>>(query, W_off, b_off, offraw, MROWS, 256);
        gemm_k256<<<dim3(2, MROWS / 64), blk, 0, stream>>>(query, W_attn, b_attn, attnraw, MROWS, 128);

        float* accp = has_acc ? accbuf : out;
        ms_sample_f32<<<dim3((NBATCH * LQ * 8) / 4), blk, 0, stream>>>(
            value, offraw, attnraw, refpts, accp);

        if (has_acc)
            gemm_k256<<<dim3(4, MROWS / 64), blk, 0, stream>>>(accbuf, W_out, b_out, out, MROWS, 256);
        else
            outproj_inplace<<<dim3(MROWS / 32), blk, 0, stream>>>(out, W_out, b_out);
    }
}